// Round 3
// baseline (3113.834 us; speedup 1.0000x reference)
//
#include <hip/hip_runtime.h>
#include <hip/hip_bf16.h>

typedef __hip_bfloat16 bf16;

#define B_  4
#define T_  1024
#define D_  512
#define H_  8
#define DK_ 64
#define L_  2047   // 2*T - 1

__device__ __forceinline__ float b2f(bf16 v) { return __bfloat162float(v); }
__device__ __forceinline__ bf16  f2b(float v) { return __float2bfloat16(v); }

template <typename T> __device__ __forceinline__ float ldf(const T* p);
template <> __device__ __forceinline__ float ldf<float>(const float* p) { return *p; }
template <> __device__ __forceinline__ float ldf<bf16>(const bf16* p) { return b2f(*p); }

// ---------------- LayerNorm: one block per (b,t) row, 256 threads ----------------
__global__ void lnorm_kernel(const float* __restrict__ x, const float* __restrict__ gamma,
                             const float* __restrict__ beta, bf16* __restrict__ y) {
    const int row = blockIdx.x;
    const float* xr = x + (size_t)row * D_;
    const int t = threadIdx.x;
    float v0 = xr[t];
    float v1 = xr[t + 256];
    float s  = v0 + v1;
    float s2 = v0 * v0 + v1 * v1;
#pragma unroll
    for (int off = 32; off > 0; off >>= 1) {
        s  += __shfl_down(s,  off, 64);
        s2 += __shfl_down(s2, off, 64);
    }
    __shared__ float ws1[4], ws2[4];
    const int wid = t >> 6, lane = t & 63;
    if (!lane) { ws1[wid] = s; ws2[wid] = s2; }
    __syncthreads();
    float S  = ws1[0] + ws1[1] + ws1[2] + ws1[3];
    float S2 = ws2[0] + ws2[1] + ws2[2] + ws2[3];
    float mean = S * (1.f / D_);
    float var  = S2 * (1.f / D_) - mean * mean;
    float r = rsqrtf(var + 1e-3f);
    bf16* yr = y + (size_t)row * D_;
    yr[t]       = f2b((v0 - mean) * r * gamma[t]       + beta[t]);
    yr[t + 256] = f2b((v1 - mean) * r * gamma[t + 256] + beta[t + 256]);
}

// ------- GEMM: [M,512] x [512,512], 64x64 tile, 4x4 per thread; W/bias/resid f32 -------
template <typename AT, typename OT>
__global__ void gemm512_kernel(const AT* __restrict__ A, const float* __restrict__ Bm,
                               const float* __restrict__ bias,   // [512] or nullptr
                               const float* __restrict__ resid,  // [M,512] or nullptr
                               OT* __restrict__ C, int M) {
    __shared__ float As[16][65];
    __shared__ float Bs[16][65];
    const int t = threadIdx.y * 16 + threadIdx.x;
    const int row0 = blockIdx.y * 64, col0 = blockIdx.x * 64;
    float acc[4][4] = {};
    for (int k0 = 0; k0 < 512; k0 += 16) {
#pragma unroll
        for (int e = 0; e < 4; ++e) {
            int idx = t + e * 256;
            int r = idx >> 4, kk = idx & 15;
            int grow = row0 + r;
            As[kk][r] = (grow < M) ? ldf(&A[(size_t)grow * 512 + k0 + kk]) : 0.f;
            int kb = idx >> 6, c = idx & 63;
            Bs[kb][c] = Bm[(size_t)(k0 + kb) * 512 + col0 + c];
        }
        __syncthreads();
#pragma unroll
        for (int kk = 0; kk < 16; ++kk) {
            float a_r[4], b_r[4];
#pragma unroll
            for (int a = 0; a < 4; ++a) a_r[a] = As[kk][threadIdx.y + 16 * a];
#pragma unroll
            for (int b = 0; b < 4; ++b) b_r[b] = Bs[kk][threadIdx.x + 16 * b];
#pragma unroll
            for (int a = 0; a < 4; ++a)
#pragma unroll
                for (int b = 0; b < 4; ++b) acc[a][b] += a_r[a] * b_r[b];
        }
        __syncthreads();
    }
#pragma unroll
    for (int a = 0; a < 4; ++a) {
        int row = row0 + threadIdx.y + 16 * a;
        if (row >= M) continue;
#pragma unroll
        for (int b = 0; b < 4; ++b) {
            int col = col0 + threadIdx.x + 16 * b;
            float vacc = acc[a][b];
            if (bias)  vacc += bias[col];
            if (resid) vacc += resid[(size_t)row * 512 + col];
            C[(size_t)row * 512 + col] = (OT)vacc;
        }
    }
}

// ---------------- Attention: one block per (b,h,i), 256 threads ----------------
// scores[j] = ( (q_i+cb)·k_j + (q_si+pb)·p_sl ) / 8 ; softmax over j; o = attn·v
// rel_shift mapping: flat = T + i*(L-1) + j ; si = flat/L ; sl = flat%L
// (si == i except the single wrap element i=0,j=T-1 -> (1,0))
__global__ void attn_kernel(const bf16* __restrict__ q, const bf16* __restrict__ k,
                            const bf16* __restrict__ v, const bf16* __restrict__ p,
                            const float* __restrict__ cbias, const float* __restrict__ pbias,
                            bf16* __restrict__ o) {
    const int i = blockIdx.x, h = blockIdx.y, b = blockIdx.z;
    const int t = threadIdx.x;
    __shared__ float qc[64], qp[64];
    __shared__ float sc[T_];
    __shared__ float red[4];
    __shared__ float part[4][64];
    const size_t qoff = (((size_t)b * T_ + i) * H_ + h) * DK_;
    if (t < 64) {
        float qv = b2f(q[qoff + t]);
        qc[t] = qv + cbias[h * 64 + t];
        qp[t] = qv + pbias[h * 64 + t];
    }
    __syncthreads();

    for (int j = t; j < T_; j += 256) {
        const bf16* kr = k + (((size_t)b * T_ + j) * H_ + h) * DK_;
        float cs = 0.f;
#pragma unroll
        for (int d = 0; d < 64; ++d) cs += qc[d] * b2f(kr[d]);
        int flat = T_ + i * (L_ - 1) + j;
        int si = flat / L_;
        int sl = flat - si * L_;
        const bf16* pr = p + (((size_t)b * L_ + sl) * H_ + h) * DK_;
        float ps = 0.f;
        if (si == i) {
#pragma unroll
            for (int d = 0; d < 64; ++d) ps += qp[d] * b2f(pr[d]);
        } else {  // single wrapped element: uses q row si, not i
            const bf16* qr = q + (((size_t)b * T_ + si) * H_ + h) * DK_;
            for (int d = 0; d < 64; ++d) ps += (b2f(qr[d]) + pbias[h * 64 + d]) * b2f(pr[d]);
        }
        sc[j] = (cs + ps) * 0.125f;
    }
    __syncthreads();

    // softmax
    float lm = -1e30f;
    for (int j = t; j < T_; j += 256) lm = fmaxf(lm, sc[j]);
#pragma unroll
    for (int off = 32; off > 0; off >>= 1) lm = fmaxf(lm, __shfl_down(lm, off, 64));
    const int wid = t >> 6, lane = t & 63;
    if (!lane) red[wid] = lm;
    __syncthreads();
    const float Mx = fmaxf(fmaxf(red[0], red[1]), fmaxf(red[2], red[3]));
    __syncthreads();
    float lsum = 0.f;
    for (int j = t; j < T_; j += 256) { float e = __expf(sc[j] - Mx); sc[j] = e; lsum += e; }
#pragma unroll
    for (int off = 32; off > 0; off >>= 1) lsum += __shfl_down(lsum, off, 64);
    if (!lane) red[wid] = lsum;
    __syncthreads();
    const float S = red[0] + red[1] + red[2] + red[3];
    const float inv = 1.f / S;

    // PV: wave w handles j-chunk w, lane covers d (coalesced v reads)
    const int d = t & 63, ch = t >> 6;
    float acc = 0.f;
    const bf16* vb = v + (((size_t)b * T_) * H_ + h) * DK_ + d;
    for (int j = ch * 256; j < ch * 256 + 256; ++j)
        acc += sc[j] * b2f(vb[(size_t)j * (H_ * DK_)]);
    part[ch][d] = acc;
    __syncthreads();
    if (t < 64)
        o[qoff + t] = f2b((part[0][t] + part[1][t] + part[2][t] + part[3][t]) * inv);
}

extern "C" void kernel_launch(void* const* d_in, const int* in_sizes, int n_in,
                              void* d_out, int out_size, void* d_ws, size_t ws_size,
                              hipStream_t stream) {
    (void)in_sizes; (void)n_in; (void)out_size;
    const float* x     = (const float*)d_in[0];
    const float* pos   = (const float*)d_in[1];
    const float* cb    = (const float*)d_in[2];
    const float* pb    = (const float*)d_in[3];
    const float* gamma = (const float*)d_in[4];
    const float* beta  = (const float*)d_in[5];
    const float* Wq    = (const float*)d_in[6];
    const float* bq    = (const float*)d_in[7];
    const float* Wk    = (const float*)d_in[8];
    const float* bk    = (const float*)d_in[9];
    const float* Wv    = (const float*)d_in[10];
    const float* bv    = (const float*)d_in[11];
    const float* Wp    = (const float*)d_in[12];
    const float* Wo    = (const float*)d_in[13];
    const float* bo    = (const float*)d_in[14];
    float* out = (float*)d_out;

    const int BT = B_ * T_;       // 4096
    const int BL = B_ * L_;       // 8188

    // workspace layout (all bf16): y,q,k,v,o = BT*512 each; p = BL*512
    const size_t sz_bt = (size_t)BT * D_;           // 2,097,152 elems
    const size_t sz_bl = (size_t)BL * D_;           // 4,192,256 elems
    const size_t need  = (5 * sz_bt + sz_bl) * sizeof(bf16);  // 29,356,032 B
    if (ws_size < need) return;  // deterministic guard: leaves out zeroed -> absmax~4.97 diagnostic

    bf16* y = (bf16*)d_ws;
    bf16* q = y + sz_bt;
    bf16* k = q + sz_bt;
    bf16* v = k + sz_bt;
    bf16* o = v + sz_bt;
    bf16* p = o + sz_bt;

    lnorm_kernel<<<BT, 256, 0, stream>>>(x, gamma, beta, y);

    dim3 thr(16, 16);
    gemm512_kernel<bf16, bf16><<<dim3(8, BT / 64), thr, 0, stream>>>(y, Wq, bq, nullptr, q, BT);
    gemm512_kernel<bf16, bf16><<<dim3(8, BT / 64), thr, 0, stream>>>(y, Wk, bk, nullptr, k, BT);
    gemm512_kernel<bf16, bf16><<<dim3(8, BT / 64), thr, 0, stream>>>(y, Wv, bv, nullptr, v, BT);
    gemm512_kernel<float, bf16><<<dim3(8, (BL + 63) / 64), thr, 0, stream>>>(pos, Wp, nullptr, nullptr, p, BL);

    attn_kernel<<<dim3(T_, H_, B_), 256, 0, stream>>>(q, k, v, p, cb, pb, o);

    gemm512_kernel<bf16, float><<<dim3(8, BT / 64), thr, 0, stream>>>(o, Wo, bo, x, out, BT);
}

// Round 4
// 614.512 us; speedup vs baseline: 5.0672x; 5.0672x over previous
//
#include <hip/hip_runtime.h>
#include <hip/hip_bf16.h>

typedef __hip_bfloat16 bf16;
typedef __attribute__((ext_vector_type(8))) short short8;
typedef __attribute__((ext_vector_type(4))) float f32x4;

#define B_  4
#define T_  1024
#define D_  512
#define H_  8
#define DK_ 64
#define L_  2047   // 2*T - 1

__device__ __forceinline__ float b2f(bf16 v) { return __bfloat162float(v); }
__device__ __forceinline__ bf16  f2b(float v) { return __float2bfloat16(v); }
__device__ __forceinline__ float bits2f(unsigned short u) {
    return __uint_as_float(((unsigned int)u) << 16);
}
template <typename T> __device__ __forceinline__ float ldf(const T* p);
template <> __device__ __forceinline__ float ldf<float>(const float* p) { return *p; }
template <> __device__ __forceinline__ float ldf<bf16>(const bf16* p) { return b2f(*p); }

#define MFMA16(a, b, c) __builtin_amdgcn_mfma_f32_16x16x32_bf16(a, b, c, 0, 0, 0)

// ---------------- LayerNorm: one block per (b,t) row, 256 threads ----------------
__global__ void lnorm_kernel(const float* __restrict__ x, const float* __restrict__ gamma,
                             const float* __restrict__ beta, bf16* __restrict__ y) {
    const int row = blockIdx.x;
    const float* xr = x + (size_t)row * D_;
    const int t = threadIdx.x;
    float v0 = xr[t];
    float v1 = xr[t + 256];
    float s  = v0 + v1;
    float s2 = v0 * v0 + v1 * v1;
#pragma unroll
    for (int off = 32; off > 0; off >>= 1) {
        s  += __shfl_down(s,  off, 64);
        s2 += __shfl_down(s2, off, 64);
    }
    __shared__ float ws1[4], ws2[4];
    const int wid = t >> 6, lane = t & 63;
    if (!lane) { ws1[wid] = s; ws2[wid] = s2; }
    __syncthreads();
    float S  = ws1[0] + ws1[1] + ws1[2] + ws1[3];
    float S2 = ws2[0] + ws2[1] + ws2[2] + ws2[3];
    float mean = S * (1.f / D_);
    float var  = S2 * (1.f / D_) - mean * mean;
    float r = rsqrtf(var + 1e-3f);
    bf16* yr = y + (size_t)row * D_;
    yr[t]       = f2b((v0 - mean) * r * gamma[t]       + beta[t]);
    yr[t + 256] = f2b((v1 - mean) * r * gamma[t + 256] + beta[t + 256]);
}

// ------- GEMM: [M,512] x [512,512], 64x64 tile, 4x4 per thread; W/bias/resid f32 -------
template <typename AT, typename OT>
__global__ void gemm512_kernel(const AT* __restrict__ A, const float* __restrict__ Bm,
                               const float* __restrict__ bias,
                               const float* __restrict__ resid,
                               OT* __restrict__ C, int M) {
    __shared__ float As[16][65];
    __shared__ float Bs[16][65];
    const int t = threadIdx.y * 16 + threadIdx.x;
    const int row0 = blockIdx.y * 64, col0 = blockIdx.x * 64;
    float acc[4][4] = {};
    for (int k0 = 0; k0 < 512; k0 += 16) {
#pragma unroll
        for (int e = 0; e < 4; ++e) {
            int idx = t + e * 256;
            int r = idx >> 4, kk = idx & 15;
            int grow = row0 + r;
            As[kk][r] = (grow < M) ? ldf(&A[(size_t)grow * 512 + k0 + kk]) : 0.f;
            int kb = idx >> 6, c = idx & 63;
            Bs[kb][c] = Bm[(size_t)(k0 + kb) * 512 + col0 + c];
        }
        __syncthreads();
#pragma unroll
        for (int kk = 0; kk < 16; ++kk) {
            float a_r[4], b_r[4];
#pragma unroll
            for (int a = 0; a < 4; ++a) a_r[a] = As[kk][threadIdx.y + 16 * a];
#pragma unroll
            for (int b = 0; b < 4; ++b) b_r[b] = Bs[kk][threadIdx.x + 16 * b];
#pragma unroll
            for (int a = 0; a < 4; ++a)
#pragma unroll
                for (int b = 0; b < 4; ++b) acc[a][b] += a_r[a] * b_r[b];
        }
        __syncthreads();
    }
#pragma unroll
    for (int a = 0; a < 4; ++a) {
        int row = row0 + threadIdx.y + 16 * a;
        if (row >= M) continue;
#pragma unroll
        for (int b = 0; b < 4; ++b) {
            int col = col0 + threadIdx.x + 16 * b;
            float vacc = acc[a][b];
            if (bias)  vacc += bias[col];
            if (resid) vacc += resid[(size_t)row * 512 + col];
            C[(size_t)row * 512 + col] = (OT)vacc;
        }
    }
}

// ---------------- Fused MFMA flash attention ----------------
// Block = (i-tile of 64 q rows, h, b), 256 threads = 4 waves; wave w owns q rows
// [i0+16w, i0+16w+16). j-loop over 16 tiles of BN=64 keys.
// scores[i][j] = ( q_i·k_j + cb·k_j + q_i·p_sl + pb·p_sl ) / 8,  sl = T-i+j
// wrap element (i=0,j=T-1): positional = (q_1+pb)·p_0, patched scalar.
__global__ __launch_bounds__(256) void attn_mfma_kernel(
        const bf16* __restrict__ q, const bf16* __restrict__ k,
        const bf16* __restrict__ v, const bf16* __restrict__ p,
        const float* __restrict__ cbias, const float* __restrict__ pbias,
        bf16* __restrict__ o) {
    __shared__ __align__(16) unsigned short q_s[64][72];
    __shared__ __align__(16) unsigned short k_s[64][72];
    __shared__ __align__(16) unsigned short vt_s[64][72];
    __shared__ __align__(16) unsigned short pw_s[128][72];   // also reused as P-buffer rows [16w,16w+16)
    __shared__ unsigned short gbuf[4][16][80];
    __shared__ float cbk_s[64];    // cb·k_j for the staged j-tile
    __shared__ float pbp_s[128];   // pb·p_sl for the staged p-window
    __shared__ float cb_s[64], pb_s[64];
    __shared__ float wrap_s;

    const int i0 = blockIdx.x * 64;
    const int h  = blockIdx.y;
    const int b  = blockIdx.z;
    const int t  = threadIdx.x;
    const int w    = t >> 6;
    const int lane = t & 63;
    const int quad = lane >> 4;
    const int n16  = lane & 15;
    const int h64  = h * 64;
    const size_t rowstride = 512;   // elements per token row in q/k/v ws ([BT][512])

    // ---- per-block setup ----
    if (t < 64)            cb_s[t]      = cbias[h64 + t];
    else if (t < 128)      pb_s[t - 64] = pbias[h64 + t - 64];
    const int srow = t >> 3;           // 0..31
    const int scol = (t & 7) * 8;      // 0..56
#pragma unroll
    for (int pass = 0; pass < 2; ++pass) {
        int r = srow + pass * 32;
        const unsigned short* src = (const unsigned short*)q +
            ((size_t)(b * T_ + i0 + r) * rowstride + h64 + scol);
        *(uint4*)&q_s[r][scol] = *(const uint4*)src;
    }
    __syncthreads();
    if (i0 == 0 && t < 64) {   // wrap positional: (q_row1 + pb)·p_row0
        float part = (b2f(((const bf16*)q)[(size_t)(b * T_ + 1) * rowstride + h64 + t]) + pb_s[t]) *
                     b2f(((const bf16*)p)[(size_t)(b * L_) * rowstride + h64 + t]);
#pragma unroll
        for (int m = 1; m < 64; m <<= 1) part += __shfl_xor(part, m, 64);
        if (t == 0) wrap_s = part;
    }

    float mrow[4], lrow[4];
    f32x4 O[4];
#pragma unroll
    for (int r = 0; r < 4; ++r) { mrow[r] = -1e30f; lrow[r] = 0.f; }
#pragma unroll
    for (int nt = 0; nt < 4; ++nt) O[nt] = (f32x4){0.f, 0.f, 0.f, 0.f};

    const int pwoff = 48 - 16 * w;     // wave's c=0 row inside pw_s

    for (int j0 = 0; j0 < T_; j0 += 64) {
        __syncthreads();   // previous iteration's LDS reads complete

        // ---- stage K tile (+cbk) ----
#pragma unroll
        for (int pass = 0; pass < 2; ++pass) {
            int jr = srow + pass * 32;
            const unsigned short* src = (const unsigned short*)k +
                ((size_t)(b * T_ + j0 + jr) * rowstride + h64 + scol);
            uint4 pk = *(const uint4*)src;
            *(uint4*)&k_s[jr][scol] = pk;
            const unsigned short* pv = (const unsigned short*)&pk;
            float part = 0.f;
#pragma unroll
            for (int e = 0; e < 8; ++e) part += cb_s[scol + e] * bits2f(pv[e]);
            part += __shfl_xor(part, 1, 64);
            part += __shfl_xor(part, 2, 64);
            part += __shfl_xor(part, 4, 64);
            if ((t & 7) == 0) cbk_s[jr] = part;
        }
        // ---- stage V^T tile ----
#pragma unroll
        for (int pass = 0; pass < 2; ++pass) {
            int jr = srow + pass * 32;
            const unsigned short* src = (const unsigned short*)v +
                ((size_t)(b * T_ + j0 + jr) * rowstride + h64 + scol);
            uint4 pk = *(const uint4*)src;
            const unsigned short* pv = (const unsigned short*)&pk;
#pragma unroll
            for (int e = 0; e < 8; ++e) vt_s[scol + e][jr] = pv[e];
        }
        // ---- stage P window (128 rows, +pbp) ----
        const int sl_base = T_ - i0 - 63 + j0;
#pragma unroll
        for (int pass = 0; pass < 4; ++pass) {
            int pr = srow + pass * 32;
            int sl = sl_base + pr;
            uint4 pk;
            if (sl < L_) {
                const unsigned short* src = (const unsigned short*)p +
                    ((size_t)(b * L_ + sl) * rowstride + h64 + scol);
                pk = *(const uint4*)src;
            } else {
                pk = (uint4){0u, 0u, 0u, 0u};
            }
            *(uint4*)&pw_s[pr][scol] = pk;
            const unsigned short* pv = (const unsigned short*)&pk;
            float part = 0.f;
#pragma unroll
            for (int e = 0; e < 8; ++e) part += pb_s[scol + e] * bits2f(pv[e]);
            part += __shfl_xor(part, 1, 64);
            part += __shfl_xor(part, 2, 64);
            part += __shfl_xor(part, 4, 64);
            if ((t & 7) == 0) pbp_s[pr] = part;
        }
        __syncthreads();

        // ---- MFMA: content scores + skewed positional G ----
        f32x4 Sc[4], G[5];
#pragma unroll
        for (int nt = 0; nt < 4; ++nt) Sc[nt] = (f32x4){0.f, 0.f, 0.f, 0.f};
#pragma unroll
        for (int ct = 0; ct < 5; ++ct) G[ct] = (f32x4){0.f, 0.f, 0.f, 0.f};
#pragma unroll
        for (int kc = 0; kc < 2; ++kc) {
            short8 a = *(const short8*)&q_s[16 * w + n16][kc * 32 + quad * 8];
#pragma unroll
            for (int nt = 0; nt < 4; ++nt) {
                short8 bk = *(const short8*)&k_s[nt * 16 + n16][kc * 32 + quad * 8];
                Sc[nt] = MFMA16(a, bk, Sc[nt]);
            }
#pragma unroll
            for (int ct = 0; ct < 5; ++ct) {
                short8 bp = *(const short8*)&pw_s[pwoff + ct * 16 + n16][kc * 32 + quad * 8];
                G[ct] = MFMA16(a, bp, G[ct]);
            }
        }
        // G -> LDS (bf16) for diagonal gather
#pragma unroll
        for (int ct = 0; ct < 5; ++ct)
#pragma unroll
            for (int r = 0; r < 4; ++r)
                *(bf16*)&gbuf[w][quad * 4 + r][ct * 16 + n16] = f2b(G[ct][r]);
        __syncthreads();

        // ---- assemble scores, online softmax ----
        float sreg[4][4];
#pragma unroll
        for (int ct = 0; ct < 4; ++ct) {
            float cbkv = cbk_s[ct * 16 + n16];
#pragma unroll
            for (int r = 0; r < 4; ++r) {
                int ii = quad * 4 + r;
                int c  = ct * 16 + n16 - ii + 15;   // 0..78
                float pos = bits2f(gbuf[w][ii][c]) + pbp_s[pwoff + c];
                sreg[ct][r] = (Sc[ct][r] + cbkv + pos) * 0.125f;
            }
        }
        if (i0 == 0 && w == 0 && j0 == 960 && lane == 15)   // wrap element (i=0, j=T-1)
            sreg[3][0] = (Sc[3][0] + cbk_s[63] + wrap_s) * 0.125f;

        float rowm[4], rowsum[4], alpha[4];
#pragma unroll
        for (int r = 0; r < 4; ++r) {
            float m = fmaxf(fmaxf(sreg[0][r], sreg[1][r]), fmaxf(sreg[2][r], sreg[3][r]));
#pragma unroll
            for (int msk = 1; msk < 16; msk <<= 1) m = fmaxf(m, __shfl_xor(m, msk, 64));
            float mn = fmaxf(mrow[r], m);
            alpha[r] = __expf(mrow[r] - mn);
            mrow[r] = mn;
            float rs = 0.f;
#pragma unroll
            for (int ct = 0; ct < 4; ++ct) {
                float pe = __expf(sreg[ct][r] - mn);
                sreg[ct][r] = pe;
                rs += pe;
            }
#pragma unroll
            for (int msk = 1; msk < 16; msk <<= 1) rs += __shfl_xor(rs, msk, 64);
            rowsum[r] = rs;
        }
#pragma unroll
        for (int r = 0; r < 4; ++r) {
            lrow[r] = lrow[r] * alpha[r] + rowsum[r];
#pragma unroll
            for (int nt = 0; nt < 4; ++nt) O[nt][r] *= alpha[r];
        }
        // P -> LDS (reuse pw_s rows [16w,16w+16)) to re-enter as A-fragments
#pragma unroll
        for (int ct = 0; ct < 4; ++ct)
#pragma unroll
            for (int r = 0; r < 4; ++r)
                *(bf16*)&pw_s[16 * w + quad * 4 + r][ct * 16 + n16] = f2b(sreg[ct][r]);

        // ---- PV ----
#pragma unroll
        for (int kc = 0; kc < 2; ++kc) {
            short8 pa = *(const short8*)&pw_s[16 * w + n16][kc * 32 + quad * 8];
#pragma unroll
            for (int nt = 0; nt < 4; ++nt) {
                short8 vb = *(const short8*)&vt_s[nt * 16 + n16][kc * 32 + quad * 8];
                O[nt] = MFMA16(pa, vb, O[nt]);
            }
        }
    }

    // ---- epilogue ----
#pragma unroll
    for (int r = 0; r < 4; ++r) {
        float inv = 1.f / lrow[r];
        int row = i0 + 16 * w + quad * 4 + r;
#pragma unroll
        for (int nt = 0; nt < 4; ++nt)
            o[(size_t)(b * T_ + row) * rowstride + h64 + nt * 16 + n16] = f2b(O[nt][r] * inv);
    }
}

extern "C" void kernel_launch(void* const* d_in, const int* in_sizes, int n_in,
                              void* d_out, int out_size, void* d_ws, size_t ws_size,
                              hipStream_t stream) {
    (void)in_sizes; (void)n_in; (void)out_size;
    const float* x     = (const float*)d_in[0];
    const float* pos   = (const float*)d_in[1];
    const float* cb    = (const float*)d_in[2];
    const float* pb    = (const float*)d_in[3];
    const float* gamma = (const float*)d_in[4];
    const float* beta  = (const float*)d_in[5];
    const float* Wq    = (const float*)d_in[6];
    const float* bq    = (const float*)d_in[7];
    const float* Wk    = (const float*)d_in[8];
    const float* bk    = (const float*)d_in[9];
    const float* Wv    = (const float*)d_in[10];
    const float* bv    = (const float*)d_in[11];
    const float* Wp    = (const float*)d_in[12];
    const float* Wo    = (const float*)d_in[13];
    const float* bo    = (const float*)d_in[14];
    float* out = (float*)d_out;

    const int BT = B_ * T_;       // 4096
    const int BL = B_ * L_;       // 8188

    const size_t sz_bt = (size_t)BT * D_;
    const size_t sz_bl = (size_t)BL * D_;
    const size_t need  = (5 * sz_bt + sz_bl) * sizeof(bf16);
    if (ws_size < need) return;

    bf16* y = (bf16*)d_ws;
    bf16* q = y + sz_bt;
    bf16* k = q + sz_bt;
    bf16* v = k + sz_bt;
    bf16* o = v + sz_bt;
    bf16* p = o + sz_bt;

    lnorm_kernel<<<BT, 256, 0, stream>>>(x, gamma, beta, y);

    dim3 thr(16, 16);
    gemm512_kernel<bf16, bf16><<<dim3(8, BT / 64), thr, 0, stream>>>(y, Wq, bq, nullptr, q, BT);
    gemm512_kernel<bf16, bf16><<<dim3(8, BT / 64), thr, 0, stream>>>(y, Wk, bk, nullptr, k, BT);
    gemm512_kernel<bf16, bf16><<<dim3(8, BT / 64), thr, 0, stream>>>(y, Wv, bv, nullptr, v, BT);
    gemm512_kernel<float, bf16><<<dim3(8, (BL + 63) / 64), thr, 0, stream>>>(pos, Wp, nullptr, nullptr, p, BL);

    attn_mfma_kernel<<<dim3(T_ / 64, H_, B_), 256, 0, stream>>>(q, k, v, p, cb, pb, o);

    gemm512_kernel<bf16, float><<<dim3(8, BT / 64), thr, 0, stream>>>(o, Wo, bo, x, out, BT);
}

// Round 5
// 288.090 us; speedup vs baseline: 10.8086x; 2.1331x over previous
//
#include <hip/hip_runtime.h>
#include <hip/hip_bf16.h>

typedef __hip_bfloat16 bf16;
typedef __attribute__((ext_vector_type(8))) short short8;
typedef __attribute__((ext_vector_type(4))) float f32x4;

#define B_  4
#define T_  1024
#define D_  512
#define H_  8
#define DK_ 64
#define L_  2047   // 2*T - 1

__device__ __forceinline__ float b2f(bf16 v) { return __bfloat162float(v); }
__device__ __forceinline__ bf16  f2b(float v) { return __float2bfloat16(v); }
__device__ __forceinline__ float bits2f(unsigned short u) {
    return __uint_as_float(((unsigned int)u) << 16);
}
__device__ __forceinline__ unsigned short fbits(float v) {
    bf16 h = f2b(v); return *(unsigned short*)&h;
}

#define MFMA16(a, b, c) __builtin_amdgcn_mfma_f32_16x16x32_bf16(a, b, c, 0, 0, 0)
#define GLD_LDS16(g, l) __builtin_amdgcn_global_load_lds( \
    (const __attribute__((address_space(1))) unsigned int*)(g), \
    (__attribute__((address_space(3))) unsigned int*)(l), 16, 0, 0)

// ---------------- LayerNorm: one block per (b,t) row, 256 threads ----------------
__global__ void lnorm_kernel(const float* __restrict__ x, const float* __restrict__ gamma,
                             const float* __restrict__ beta, bf16* __restrict__ y) {
    const int row = blockIdx.x;
    const float* xr = x + (size_t)row * D_;
    const int t = threadIdx.x;
    float v0 = xr[t];
    float v1 = xr[t + 256];
    float s  = v0 + v1;
    float s2 = v0 * v0 + v1 * v1;
#pragma unroll
    for (int off = 32; off > 0; off >>= 1) {
        s  += __shfl_down(s,  off, 64);
        s2 += __shfl_down(s2, off, 64);
    }
    __shared__ float ws1[4], ws2[4];
    const int wid = t >> 6, lane = t & 63;
    if (!lane) { ws1[wid] = s; ws2[wid] = s2; }
    __syncthreads();
    float S  = ws1[0] + ws1[1] + ws1[2] + ws1[3];
    float S2 = ws2[0] + ws2[1] + ws2[2] + ws2[3];
    float mean = S * (1.f / D_);
    float var  = S2 * (1.f / D_) - mean * mean;
    float r = rsqrtf(var + 1e-3f);
    bf16* yr = y + (size_t)row * D_;
    yr[t]       = f2b((v0 - mean) * r * gamma[t]       + beta[t]);
    yr[t + 256] = f2b((v1 - mean) * r * gamma[t + 256] + beta[t + 256]);
}

// ---------- weight prep: W f32 [512][512] -> Wt bf16 [512(n)+off][512(k)] ----------
__global__ void prep_weights(const float* __restrict__ Wq, const float* __restrict__ Wk,
                             const float* __restrict__ Wv, const float* __restrict__ Wp,
                             const float* __restrict__ Wo,
                             bf16* __restrict__ Wqkv_t, bf16* __restrict__ Wp_t,
                             bf16* __restrict__ Wo_t) {
    const float* W; bf16* Wt; int roff;
    switch (blockIdx.z) {
        case 0: W = Wq; Wt = Wqkv_t; roff = 0;    break;
        case 1: W = Wk; Wt = Wqkv_t; roff = 512;  break;
        case 2: W = Wv; Wt = Wqkv_t; roff = 1024; break;
        case 3: W = Wp; Wt = Wp_t;   roff = 0;    break;
        default: W = Wo; Wt = Wo_t;  roff = 0;    break;
    }
    __shared__ float tl[32][33];
    const int n0 = blockIdx.x * 32, k0 = blockIdx.y * 32;
    const int tx = threadIdx.x, ty = threadIdx.y;   // (32, 8)
#pragma unroll
    for (int r = 0; r < 4; ++r)
        tl[ty + r * 8][tx] = W[(size_t)(k0 + ty + r * 8) * 512 + n0 + tx];
    __syncthreads();
#pragma unroll
    for (int r = 0; r < 4; ++r)
        Wt[(size_t)(roff + n0 + ty + r * 8) * 512 + k0 + tx] = f2b(tl[tx][ty + r * 8]);
}

__global__ void concat_bias(const float* __restrict__ bq, const float* __restrict__ bk,
                            const float* __restrict__ bv, float* __restrict__ bias) {
    int i = blockIdx.x * 256 + threadIdx.x;   // 0..1535
    float v = (i < 512) ? bq[i] : (i < 1024) ? bk[i - 512] : bv[i - 1024];
    bias[i] = v;
}

// ---------------- MFMA GEMM: [M,512] x Wt^T (Wt: [N][512] bf16) ----------------
// 128x128 tile, BK=32, 256 thr = 2x2 waves, each wave 64x64 via 4x4 mfma16x16x32.
// Output columns are split into 512-wide segments: C_seg = Cbase + (n>>9)*seg_elems.
template <bool A_F32, bool C_F32>
__global__ __launch_bounds__(256) void gemm_mfma(
        const void* __restrict__ Av, const bf16* __restrict__ Wt,
        const float* __restrict__ bias, const float* __restrict__ resid,
        void* __restrict__ Cv, int M, size_t seg_elems) {
    __shared__ __align__(16) unsigned short A_s[128][32];
    __shared__ __align__(16) unsigned short B_s[128][32];
    const int t = threadIdx.x;
    const int w = t >> 6, lane = t & 63;
    const int quad = lane >> 4, n16 = lane & 15;
    const int m0 = blockIdx.y * 128, n0 = blockIdx.x * 128;
    const int wm = (w >> 1) * 64, wn = (w & 1) * 64;

    f32x4 acc[4][4];
#pragma unroll
    for (int a = 0; a < 4; ++a)
#pragma unroll
        for (int b = 0; b < 4; ++b) acc[a][b] = (f32x4){0.f, 0.f, 0.f, 0.f};

    for (int k0 = 0; k0 < 512; k0 += 32) {
        __syncthreads();
        if constexpr (!A_F32) {
            const bf16* A = (const bf16*)Av;
#pragma unroll
            for (int ps = 0; ps < 2; ++ps) {
                int br = (ps * 4 + w) * 16;
                const bf16* gp = A + (size_t)(m0 + br + (lane >> 2)) * 512 + k0 + (lane & 3) * 8;
                GLD_LDS16(gp, &A_s[br][0]);
            }
        } else {
            const float* A = (const float*)Av;
            int r = t >> 1, c = (t & 1) * 16;
            int gr = m0 + r;
            unsigned int pk[8] = {0, 0, 0, 0, 0, 0, 0, 0};
            if (gr < M) {
                const float* src = A + (size_t)gr * 512 + k0 + c;
#pragma unroll
                for (int e = 0; e < 4; ++e) {
                    float4 f = *(const float4*)(src + 4 * e);
                    pk[2 * e + 0] = ((unsigned)fbits(f.y) << 16) | fbits(f.x);
                    pk[2 * e + 1] = ((unsigned)fbits(f.w) << 16) | fbits(f.z);
                }
            }
            *(uint4*)&A_s[r][c]     = *(uint4*)&pk[0];
            *(uint4*)&A_s[r][c + 8] = *(uint4*)&pk[4];
        }
#pragma unroll
        for (int ps = 0; ps < 2; ++ps) {
            int br = (ps * 4 + w) * 16;
            const bf16* gp = Wt + (size_t)(n0 + br + (lane >> 2)) * 512 + k0 + (lane & 3) * 8;
            GLD_LDS16(gp, &B_s[br][0]);
        }
        __syncthreads();

        short8 af[4], bfr[4];
#pragma unroll
        for (int i = 0; i < 4; ++i) {
            af[i]  = *(const short8*)&A_s[wm + i * 16 + n16][quad * 8];
            bfr[i] = *(const short8*)&B_s[wn + i * 16 + n16][quad * 8];
        }
#pragma unroll
        for (int mi = 0; mi < 4; ++mi)
#pragma unroll
            for (int ni = 0; ni < 4; ++ni)
                acc[mi][ni] = MFMA16(af[mi], bfr[ni], acc[mi][ni]);
    }

    const int seg = n0 >> 9;
#pragma unroll
    for (int mi = 0; mi < 4; ++mi) {
#pragma unroll
        for (int r = 0; r < 4; ++r) {
            int row = m0 + wm + mi * 16 + quad * 4 + r;
            if (row >= M) continue;
#pragma unroll
            for (int ni = 0; ni < 4; ++ni) {
                int col  = n0 + wn + ni * 16 + n16;     // global col (bias index)
                int coll = col & 511;                   // col within segment
                float vv = acc[mi][ni][r];
                if (bias) vv += bias[col];
                if constexpr (C_F32) {
                    float* C = (float*)Cv + seg * seg_elems;
                    if (resid) vv += resid[(size_t)row * 512 + coll];
                    C[(size_t)row * 512 + coll] = vv;
                } else {
                    bf16* C = (bf16*)Cv + seg * seg_elems;
                    C[(size_t)row * 512 + coll] = f2b(vv);
                }
            }
        }
    }
}

// ---------------- Fused MFMA flash attention ----------------
// Block = (i-tile of 64 q rows, h, b), 256 threads = 4 waves; wave w owns q rows
// [i0+16w, i0+16w+16). j-loop over 16 tiles of BN=64 keys.
// scores[i][j] = ( q_i·k_j + cb·k_j + q_i·p_sl + pb·p_sl ) / 8,  sl = T-i+j
// wrap element (i=0,j=T-1): positional = (q_1+pb)·p_0, patched scalar.
__global__ __launch_bounds__(256) void attn_mfma_kernel(
        const bf16* __restrict__ q, const bf16* __restrict__ k,
        const bf16* __restrict__ v, const bf16* __restrict__ p,
        const float* __restrict__ cbias, const float* __restrict__ pbias,
        bf16* __restrict__ o) {
    __shared__ __align__(16) unsigned short q_s[64][72];
    __shared__ __align__(16) unsigned short k_s[64][72];
    __shared__ __align__(16) unsigned short vt_s[64][72];
    __shared__ __align__(16) unsigned short pw_s[128][72];
    __shared__ unsigned short gbuf[4][16][80];
    __shared__ float cbk_s[64];
    __shared__ float pbp_s[128];
    __shared__ float cb_s[64], pb_s[64];
    __shared__ float wrap_s;

    const int i0 = blockIdx.x * 64;
    const int h  = blockIdx.y;
    const int b  = blockIdx.z;
    const int t  = threadIdx.x;
    const int w    = t >> 6;
    const int lane = t & 63;
    const int quad = lane >> 4;
    const int n16  = lane & 15;
    const int h64  = h * 64;
    const size_t rowstride = 512;

    if (t < 64)            cb_s[t]      = cbias[h64 + t];
    else if (t < 128)      pb_s[t - 64] = pbias[h64 + t - 64];
    const int srow = t >> 3;
    const int scol = (t & 7) * 8;
#pragma unroll
    for (int pass = 0; pass < 2; ++pass) {
        int r = srow + pass * 32;
        const unsigned short* src = (const unsigned short*)q +
            ((size_t)(b * T_ + i0 + r) * rowstride + h64 + scol);
        *(uint4*)&q_s[r][scol] = *(const uint4*)src;
    }
    __syncthreads();
    if (i0 == 0 && t < 64) {
        float part = (b2f(((const bf16*)q)[(size_t)(b * T_ + 1) * rowstride + h64 + t]) + pb_s[t]) *
                     b2f(((const bf16*)p)[(size_t)(b * L_) * rowstride + h64 + t]);
#pragma unroll
        for (int m = 1; m < 64; m <<= 1) part += __shfl_xor(part, m, 64);
        if (t == 0) wrap_s = part;
    }

    float mrow[4], lrow[4];
    f32x4 O[4];
#pragma unroll
    for (int r = 0; r < 4; ++r) { mrow[r] = -1e30f; lrow[r] = 0.f; }
#pragma unroll
    for (int nt = 0; nt < 4; ++nt) O[nt] = (f32x4){0.f, 0.f, 0.f, 0.f};

    const int pwoff = 48 - 16 * w;

    for (int j0 = 0; j0 < T_; j0 += 64) {
        __syncthreads();

#pragma unroll
        for (int pass = 0; pass < 2; ++pass) {
            int jr = srow + pass * 32;
            const unsigned short* src = (const unsigned short*)k +
                ((size_t)(b * T_ + j0 + jr) * rowstride + h64 + scol);
            uint4 pk = *(const uint4*)src;
            *(uint4*)&k_s[jr][scol] = pk;
            const unsigned short* pv = (const unsigned short*)&pk;
            float part = 0.f;
#pragma unroll
            for (int e = 0; e < 8; ++e) part += cb_s[scol + e] * bits2f(pv[e]);
            part += __shfl_xor(part, 1, 64);
            part += __shfl_xor(part, 2, 64);
            part += __shfl_xor(part, 4, 64);
            if ((t & 7) == 0) cbk_s[jr] = part;
        }
#pragma unroll
        for (int pass = 0; pass < 2; ++pass) {
            int jr = srow + pass * 32;
            const unsigned short* src = (const unsigned short*)v +
                ((size_t)(b * T_ + j0 + jr) * rowstride + h64 + scol);
            uint4 pk = *(const uint4*)src;
            const unsigned short* pv = (const unsigned short*)&pk;
#pragma unroll
            for (int e = 0; e < 8; ++e) vt_s[scol + e][jr] = pv[e];
        }
        const int sl_base = T_ - i0 - 63 + j0;
#pragma unroll
        for (int pass = 0; pass < 4; ++pass) {
            int pr = srow + pass * 32;
            int sl = sl_base + pr;
            uint4 pk;
            if (sl < L_) {
                const unsigned short* src = (const unsigned short*)p +
                    ((size_t)(b * L_ + sl) * rowstride + h64 + scol);
                pk = *(const uint4*)src;
            } else {
                pk = (uint4){0u, 0u, 0u, 0u};
            }
            *(uint4*)&pw_s[pr][scol] = pk;
            const unsigned short* pv = (const unsigned short*)&pk;
            float part = 0.f;
#pragma unroll
            for (int e = 0; e < 8; ++e) part += pb_s[scol + e] * bits2f(pv[e]);
            part += __shfl_xor(part, 1, 64);
            part += __shfl_xor(part, 2, 64);
            part += __shfl_xor(part, 4, 64);
            if ((t & 7) == 0) pbp_s[pr] = part;
        }
        __syncthreads();

        f32x4 Sc[4], G[5];
#pragma unroll
        for (int nt = 0; nt < 4; ++nt) Sc[nt] = (f32x4){0.f, 0.f, 0.f, 0.f};
#pragma unroll
        for (int ct = 0; ct < 5; ++ct) G[ct] = (f32x4){0.f, 0.f, 0.f, 0.f};
#pragma unroll
        for (int kc = 0; kc < 2; ++kc) {
            short8 a = *(const short8*)&q_s[16 * w + n16][kc * 32 + quad * 8];
#pragma unroll
            for (int nt = 0; nt < 4; ++nt) {
                short8 bk = *(const short8*)&k_s[nt * 16 + n16][kc * 32 + quad * 8];
                Sc[nt] = MFMA16(a, bk, Sc[nt]);
            }
#pragma unroll
            for (int ct = 0; ct < 5; ++ct) {
                short8 bp = *(const short8*)&pw_s[pwoff + ct * 16 + n16][kc * 32 + quad * 8];
                G[ct] = MFMA16(a, bp, G[ct]);
            }
        }
#pragma unroll
        for (int ct = 0; ct < 5; ++ct)
#pragma unroll
            for (int r = 0; r < 4; ++r)
                *(bf16*)&gbuf[w][quad * 4 + r][ct * 16 + n16] = f2b(G[ct][r]);
        __syncthreads();

        float sreg[4][4];
#pragma unroll
        for (int ct = 0; ct < 4; ++ct) {
            float cbkv = cbk_s[ct * 16 + n16];
#pragma unroll
            for (int r = 0; r < 4; ++r) {
                int ii = quad * 4 + r;
                int c  = ct * 16 + n16 - ii + 15;
                float pos = bits2f(gbuf[w][ii][c]) + pbp_s[pwoff + c];
                sreg[ct][r] = (Sc[ct][r] + cbkv + pos) * 0.125f;
            }
        }
        if (i0 == 0 && w == 0 && j0 == 960 && lane == 15)
            sreg[3][0] = (Sc[3][0] + cbk_s[63] + wrap_s) * 0.125f;

        float rowsum[4], alpha[4];
#pragma unroll
        for (int r = 0; r < 4; ++r) {
            float m = fmaxf(fmaxf(sreg[0][r], sreg[1][r]), fmaxf(sreg[2][r], sreg[3][r]));
#pragma unroll
            for (int msk = 1; msk < 16; msk <<= 1) m = fmaxf(m, __shfl_xor(m, msk, 64));
            float mn = fmaxf(mrow[r], m);
            alpha[r] = __expf(mrow[r] - mn);
            mrow[r] = mn;
            float rs = 0.f;
#pragma unroll
            for (int ct = 0; ct < 4; ++ct) {
                float pe = __expf(sreg[ct][r] - mn);
                sreg[ct][r] = pe;
                rs += pe;
            }
#pragma unroll
            for (int msk = 1; msk < 16; msk <<= 1) rs += __shfl_xor(rs, msk, 64);
            rowsum[r] = rs;
        }
#pragma unroll
        for (int r = 0; r < 4; ++r) {
            lrow[r] = lrow[r] * alpha[r] + rowsum[r];
#pragma unroll
            for (int nt = 0; nt < 4; ++nt) O[nt][r] *= alpha[r];
        }
#pragma unroll
        for (int ct = 0; ct < 4; ++ct)
#pragma unroll
            for (int r = 0; r < 4; ++r)
                *(bf16*)&pw_s[16 * w + quad * 4 + r][ct * 16 + n16] = f2b(sreg[ct][r]);

#pragma unroll
        for (int kc = 0; kc < 2; ++kc) {
            short8 pa = *(const short8*)&pw_s[16 * w + n16][kc * 32 + quad * 8];
#pragma unroll
            for (int nt = 0; nt < 4; ++nt) {
                short8 vb = *(const short8*)&vt_s[nt * 16 + n16][kc * 32 + quad * 8];
                O[nt] = MFMA16(pa, vb, O[nt]);
            }
        }
    }

#pragma unroll
    for (int r = 0; r < 4; ++r) {
        float inv = 1.f / lrow[r];
        int row = i0 + 16 * w + quad * 4 + r;
#pragma unroll
        for (int nt = 0; nt < 4; ++nt)
            o[(size_t)(b * T_ + row) * rowstride + h64 + nt * 16 + n16] = f2b(O[nt][r] * inv);
    }
}

extern "C" void kernel_launch(void* const* d_in, const int* in_sizes, int n_in,
                              void* d_out, int out_size, void* d_ws, size_t ws_size,
                              hipStream_t stream) {
    (void)in_sizes; (void)n_in; (void)out_size;
    const float* x     = (const float*)d_in[0];
    const float* pos   = (const float*)d_in[1];
    const float* cb    = (const float*)d_in[2];
    const float* pb    = (const float*)d_in[3];
    const float* gamma = (const float*)d_in[4];
    const float* beta  = (const float*)d_in[5];
    const float* Wq    = (const float*)d_in[6];
    const float* bq    = (const float*)d_in[7];
    const float* Wk    = (const float*)d_in[8];
    const float* bk    = (const float*)d_in[9];
    const float* Wv    = (const float*)d_in[10];
    const float* bv    = (const float*)d_in[11];
    const float* Wp    = (const float*)d_in[12];
    const float* Wo    = (const float*)d_in[13];
    const float* bo    = (const float*)d_in[14];
    float* out = (float*)d_out;

    const int BT = B_ * T_;       // 4096
    const int BL = B_ * L_;       // 8188

    const size_t sz_bt = (size_t)BT * D_;      // 2,097,152
    const size_t sz_bl = (size_t)BL * D_;      // 4,192,256
    const size_t sz_w  = 512 * 512;            // 262,144
    const size_t need  = (5 * sz_bt + sz_bl + 5 * sz_w) * sizeof(bf16) + 1536 * sizeof(float);
    if (ws_size < need) return;   // diagnostic: zero out -> absmax~4.97

    bf16* y       = (bf16*)d_ws;
    bf16* q       = y + sz_bt;
    bf16* k       = q + sz_bt;
    bf16* v       = k + sz_bt;
    bf16* o       = v + sz_bt;
    bf16* p       = o + sz_bt;
    bf16* Wqkv_t  = p + sz_bl;
    bf16* Wp_t    = Wqkv_t + 3 * sz_w;
    bf16* Wo_t    = Wp_t + sz_w;
    float* biasq  = (float*)(Wo_t + sz_w);

    prep_weights<<<dim3(16, 16, 5), dim3(32, 8), 0, stream>>>(Wq, Wk, Wv, Wp, Wo,
                                                              Wqkv_t, Wp_t, Wo_t);
    concat_bias<<<6, 256, 0, stream>>>(bq, bk, bv, biasq);
    lnorm_kernel<<<BT, 256, 0, stream>>>(x, gamma, beta, y);

    // q|k|v fused: [4096,512] x [512,1536]
    gemm_mfma<false, false><<<dim3(12, 32), 256, 0, stream>>>(
        y, Wqkv_t, biasq, nullptr, q, BT, sz_bt);
    // p: [8188,512] x [512,512], f32 A
    gemm_mfma<true, false><<<dim3(4, 64), 256, 0, stream>>>(
        pos, Wp_t, nullptr, nullptr, p, BL, 0);

    attn_mfma_kernel<<<dim3(T_ / 64, H_, B_), 256, 0, stream>>>(q, k, v, p, cb, pb, o);

    // out: [4096,512] x [512,512] + bo + x residual -> f32 d_out
    gemm_mfma<false, true><<<dim3(4, 32), 256, 0, stream>>>(
        o, Wo_t, bo, x, out, BT, 0);
}

// Round 6
// 264.325 us; speedup vs baseline: 11.7803x; 1.0899x over previous
//
#include <hip/hip_runtime.h>
#include <hip/hip_bf16.h>

typedef __hip_bfloat16 bf16;
typedef __attribute__((ext_vector_type(8))) short short8;
typedef __attribute__((ext_vector_type(4))) float f32x4;

#define B_  4
#define T_  1024
#define D_  512
#define H_  8
#define DK_ 64
#define L_  2047   // 2*T - 1

__device__ __forceinline__ float b2f(bf16 v) { return __bfloat162float(v); }
__device__ __forceinline__ bf16  f2b(float v) { return __float2bfloat16(v); }
__device__ __forceinline__ float bits2f(unsigned short u) {
    return __uint_as_float(((unsigned int)u) << 16);
}
__device__ __forceinline__ unsigned short fbits(float v) {
    bf16 h = f2b(v); return *(unsigned short*)&h;
}

#define MFMA16(a, b, c) __builtin_amdgcn_mfma_f32_16x16x32_bf16(a, b, c, 0, 0, 0)
#define GLD_LDS16(g, l) __builtin_amdgcn_global_load_lds( \
    (const __attribute__((address_space(1))) unsigned int*)(g), \
    (__attribute__((address_space(3))) unsigned int*)(l), 16, 0, 0)

// ---------------- LayerNorm: one block per (b,t) row, 256 threads ----------------
__global__ void lnorm_kernel(const float* __restrict__ x, const float* __restrict__ gamma,
                             const float* __restrict__ beta, bf16* __restrict__ y) {
    const int row = blockIdx.x;
    const float* xr = x + (size_t)row * D_;
    const int t = threadIdx.x;
    float v0 = xr[t];
    float v1 = xr[t + 256];
    float s  = v0 + v1;
    float s2 = v0 * v0 + v1 * v1;
#pragma unroll
    for (int off = 32; off > 0; off >>= 1) {
        s  += __shfl_down(s,  off, 64);
        s2 += __shfl_down(s2, off, 64);
    }
    __shared__ float ws1[4], ws2[4];
    const int wid = t >> 6, lane = t & 63;
    if (!lane) { ws1[wid] = s; ws2[wid] = s2; }
    __syncthreads();
    float S  = ws1[0] + ws1[1] + ws1[2] + ws1[3];
    float S2 = ws2[0] + ws2[1] + ws2[2] + ws2[3];
    float mean = S * (1.f / D_);
    float var  = S2 * (1.f / D_) - mean * mean;
    float r = rsqrtf(var + 1e-3f);
    bf16* yr = y + (size_t)row * D_;
    yr[t]       = f2b((v0 - mean) * r * gamma[t]       + beta[t]);
    yr[t + 256] = f2b((v1 - mean) * r * gamma[t + 256] + beta[t + 256]);
}

// ---------- weight prep: W f32 [512][512] -> Wt bf16 [512(n)+off][512(k)] ----------
__global__ void prep_weights(const float* __restrict__ Wq, const float* __restrict__ Wk,
                             const float* __restrict__ Wv, const float* __restrict__ Wp,
                             const float* __restrict__ Wo,
                             bf16* __restrict__ Wqkv_t, bf16* __restrict__ Wp_t,
                             bf16* __restrict__ Wo_t) {
    const float* W; bf16* Wt; int roff;
    switch (blockIdx.z) {
        case 0: W = Wq; Wt = Wqkv_t; roff = 0;    break;
        case 1: W = Wk; Wt = Wqkv_t; roff = 512;  break;
        case 2: W = Wv; Wt = Wqkv_t; roff = 1024; break;
        case 3: W = Wp; Wt = Wp_t;   roff = 0;    break;
        default: W = Wo; Wt = Wo_t;  roff = 0;    break;
    }
    __shared__ float tl[32][33];
    const int n0 = blockIdx.x * 32, k0 = blockIdx.y * 32;
    const int tx = threadIdx.x, ty = threadIdx.y;   // (32, 8)
#pragma unroll
    for (int r = 0; r < 4; ++r)
        tl[ty + r * 8][tx] = W[(size_t)(k0 + ty + r * 8) * 512 + n0 + tx];
    __syncthreads();
#pragma unroll
    for (int r = 0; r < 4; ++r)
        Wt[(size_t)(roff + n0 + ty + r * 8) * 512 + k0 + tx] = f2b(tl[tx][ty + r * 8]);
}

__global__ void concat_bias(const float* __restrict__ bq, const float* __restrict__ bk,
                            const float* __restrict__ bv, float* __restrict__ bias) {
    int i = blockIdx.x * 256 + threadIdx.x;   // 0..1535
    float v = (i < 512) ? bq[i] : (i < 1024) ? bk[i - 512] : bv[i - 1024];
    bias[i] = v;
}

// ---------- pos f32 -> bf16 (8 elems/thread, exact grid) ----------
__global__ void pos_cvt(const float* __restrict__ src, bf16* __restrict__ dst) {
    size_t i = ((size_t)blockIdx.x * 256 + threadIdx.x) * 8;
    float4 a = *(const float4*)(src + i);
    float4 c = *(const float4*)(src + i + 4);
    uint4 wv;
    wv.x = ((unsigned)fbits(a.y) << 16) | fbits(a.x);
    wv.y = ((unsigned)fbits(a.w) << 16) | fbits(a.z);
    wv.z = ((unsigned)fbits(c.y) << 16) | fbits(c.x);
    wv.w = ((unsigned)fbits(c.w) << 16) | fbits(c.z);
    *(uint4*)((unsigned short*)dst + i) = wv;
}

// ---------------- MFMA GEMM: [M,512] x Wt^T (Wt: [N][512] bf16) ----------------
// 128x128 tile, BK=32, 256 thr = 2x2 waves, each wave 64x64 via 4x4 mfma16x16x32.
// Output columns split into 512-wide segments: C_seg = Cbase + (n>>9)*seg_elems.
template <bool C_F32>
__global__ __launch_bounds__(256) void gemm_mfma(
        const bf16* __restrict__ A, const bf16* __restrict__ Wt,
        const float* __restrict__ bias, const float* __restrict__ resid,
        void* __restrict__ Cv, int M, size_t seg_elems) {
    __shared__ __align__(16) unsigned short A_s[128][32];
    __shared__ __align__(16) unsigned short B_s[128][32];
    const int t = threadIdx.x;
    const int w = t >> 6, lane = t & 63;
    const int quad = lane >> 4, n16 = lane & 15;
    const int m0 = blockIdx.y * 128, n0 = blockIdx.x * 128;
    const int wm = (w >> 1) * 64, wn = (w & 1) * 64;

    f32x4 acc[4][4];
#pragma unroll
    for (int a = 0; a < 4; ++a)
#pragma unroll
        for (int b = 0; b < 4; ++b) acc[a][b] = (f32x4){0.f, 0.f, 0.f, 0.f};

    for (int k0 = 0; k0 < 512; k0 += 32) {
        __syncthreads();
#pragma unroll
        for (int ps = 0; ps < 2; ++ps) {
            int br = (ps * 4 + w) * 16;
            const bf16* gp = A + (size_t)(m0 + br + (lane >> 2)) * 512 + k0 + (lane & 3) * 8;
            GLD_LDS16(gp, &A_s[br][0]);
        }
#pragma unroll
        for (int ps = 0; ps < 2; ++ps) {
            int br = (ps * 4 + w) * 16;
            const bf16* gp = Wt + (size_t)(n0 + br + (lane >> 2)) * 512 + k0 + (lane & 3) * 8;
            GLD_LDS16(gp, &B_s[br][0]);
        }
        __syncthreads();

        short8 af[4], bfr[4];
#pragma unroll
        for (int i = 0; i < 4; ++i) {
            af[i]  = *(const short8*)&A_s[wm + i * 16 + n16][quad * 8];
            bfr[i] = *(const short8*)&B_s[wn + i * 16 + n16][quad * 8];
        }
#pragma unroll
        for (int mi = 0; mi < 4; ++mi)
#pragma unroll
            for (int ni = 0; ni < 4; ++ni)
                acc[mi][ni] = MFMA16(af[mi], bfr[ni], acc[mi][ni]);
    }

    const int seg = n0 >> 9;
#pragma unroll
    for (int mi = 0; mi < 4; ++mi) {
#pragma unroll
        for (int r = 0; r < 4; ++r) {
            int row = m0 + wm + mi * 16 + quad * 4 + r;
            if (row >= M) continue;
#pragma unroll
            for (int ni = 0; ni < 4; ++ni) {
                int col  = n0 + wn + ni * 16 + n16;
                int coll = col & 511;
                float vv = acc[mi][ni][r];
                if (bias) vv += bias[col];
                if constexpr (C_F32) {
                    float* C = (float*)Cv + seg * seg_elems;
                    if (resid) vv += resid[(size_t)row * 512 + coll];
                    C[(size_t)row * 512 + coll] = vv;
                } else {
                    bf16* C = (bf16*)Cv + seg * seg_elems;
                    C[(size_t)row * 512 + coll] = f2b(vv);
                }
            }
        }
    }
}

// ---------------- Fused MFMA flash attention ----------------
// Block = (i-tile of 64 q rows, h, b); wave w owns q rows [i0+16w, i0+16w+16).
// qc_s = q + cb staged once; positional A-fragment = qc + (pb-cb) built in-register.
// scores = ( (q+cb)·k_j + (q+pb)·p_sl ) * (1/8); softmax in base-2 domain.
// wrap element (i=0,j=T-1): positional = (q_1+pb)·p_0, patched scalar.
__global__ __launch_bounds__(256) void attn_mfma_kernel(
        const bf16* __restrict__ q, const bf16* __restrict__ k,
        const bf16* __restrict__ v, const bf16* __restrict__ p,
        const float* __restrict__ cbias, const float* __restrict__ pbias,
        bf16* __restrict__ o) {
    __shared__ __align__(16) unsigned short qc_s[64][72];
    __shared__ __align__(16) unsigned short k_s[64][72];
    __shared__ __align__(16) unsigned short vt_s[64][72];
    __shared__ __align__(16) unsigned short pw_s[128][72];
    __shared__ unsigned short gbuf[4][16][82];   // 82: quads land on banks 0/4/8/12
    __shared__ float cb_s[64], pb_s[64];
    __shared__ float wrap_s;

    const int i0 = blockIdx.x * 64;
    const int h  = blockIdx.y;
    const int b  = blockIdx.z;
    const int t  = threadIdx.x;
    const int w    = t >> 6;
    const int lane = t & 63;
    const int quad = lane >> 4;
    const int n16  = lane & 15;
    const int h64  = h * 64;

    if (t < 64)            cb_s[t]      = cbias[h64 + t];
    else if (t < 128)      pb_s[t - 64] = pbias[h64 + t - 64];
    __syncthreads();

    // ---- stage q + cb ----
    const int srow = t >> 3;           // 0..31
    const int scol = (t & 7) * 8;      // 0..56
#pragma unroll
    for (int pass = 0; pass < 2; ++pass) {
        int r = srow + pass * 32;
        const unsigned short* src = (const unsigned short*)q +
            ((size_t)(b * T_ + i0 + r) * 512 + h64 + scol);
        uint4 pk = *(const uint4*)src;
        const unsigned short* pv = (const unsigned short*)&pk;
        uint4 wd;
        unsigned int* wdp = (unsigned int*)&wd;
#pragma unroll
        for (int e2 = 0; e2 < 4; ++e2) {
            unsigned short lo = fbits(bits2f(pv[2 * e2])     + cb_s[scol + 2 * e2]);
            unsigned short hi = fbits(bits2f(pv[2 * e2 + 1]) + cb_s[scol + 2 * e2 + 1]);
            wdp[e2] = ((unsigned)hi << 16) | lo;
        }
        *(uint4*)&qc_s[r][scol] = wd;
    }
    // per-lane (pb-cb) A-fragment deltas (k = kc*32 + quad*8 + e)
    float dl[2][8];
#pragma unroll
    for (int kc = 0; kc < 2; ++kc)
#pragma unroll
        for (int e = 0; e < 8; ++e) {
            int d = kc * 32 + quad * 8 + e;
            dl[kc][e] = pb_s[d] - cb_s[d];
        }
    __syncthreads();
    if (i0 == 0 && t < 64) {   // wrap positional: (q_1 + pb)·p_0
        float part = (bits2f(qc_s[1][t]) + pb_s[t] - cb_s[t]) *
                     b2f(p[(size_t)(b * L_) * 512 + h64 + t]);
#pragma unroll
        for (int m = 1; m < 64; m <<= 1) part += __shfl_xor(part, m, 64);
        if (t == 0) wrap_s = part;
    }

    float mrow[4], lrow[4];
    f32x4 O[4];
#pragma unroll
    for (int r = 0; r < 4; ++r) { mrow[r] = -1e30f; lrow[r] = 0.f; }
#pragma unroll
    for (int nt = 0; nt < 4; ++nt) O[nt] = (f32x4){0.f, 0.f, 0.f, 0.f};

    const int pwoff = 48 - 16 * w;
    const float sc_scale = 0.125f * 1.4426950408889634f;   // (1/8)·log2(e)

    for (int j0 = 0; j0 < T_; j0 += 64) {
        __syncthreads();

        // ---- K tile (vector copy) ----
#pragma unroll
        for (int pass = 0; pass < 2; ++pass) {
            int jr = srow + pass * 32;
            const unsigned short* src = (const unsigned short*)k +
                ((size_t)(b * T_ + j0 + jr) * 512 + h64 + scol);
            *(uint4*)&k_s[jr][scol] = *(const uint4*)src;
        }
        // ---- V tile, transposed: d-major dword loads + b128 LDS writes ----
        {
            const int d2 = (t & 31) * 2;     // even d
            const int jg = t >> 5;           // 0..7, j = jg*8 + e
            unsigned int u[8];
            const unsigned short* vg = (const unsigned short*)v +
                ((size_t)(b * T_ + j0 + jg * 8) * 512 + h64 + d2);
#pragma unroll
            for (int e = 0; e < 8; ++e) u[e] = *(const unsigned int*)(vg + (size_t)e * 512);
            uint4 wlo, whi;
            wlo.x = (u[0] & 0xffffu) | (u[1] << 16);
            wlo.y = (u[2] & 0xffffu) | (u[3] << 16);
            wlo.z = (u[4] & 0xffffu) | (u[5] << 16);
            wlo.w = (u[6] & 0xffffu) | (u[7] << 16);
            whi.x = (u[0] >> 16) | (u[1] & 0xffff0000u);
            whi.y = (u[2] >> 16) | (u[3] & 0xffff0000u);
            whi.z = (u[4] >> 16) | (u[5] & 0xffff0000u);
            whi.w = (u[6] >> 16) | (u[7] & 0xffff0000u);
            *(uint4*)&vt_s[d2][jg * 8]     = wlo;
            *(uint4*)&vt_s[d2 + 1][jg * 8] = whi;
        }
        // ---- P window (vector copy) ----
        const int sl_base = T_ - i0 - 63 + j0;
#pragma unroll
        for (int pass = 0; pass < 4; ++pass) {
            int pr = srow + pass * 32;
            int sl = sl_base + pr;
            uint4 pk = (uint4){0u, 0u, 0u, 0u};
            if (sl < L_)
                pk = *(const uint4*)((const unsigned short*)p +
                     ((size_t)(b * L_ + sl) * 512 + h64 + scol));
            *(uint4*)&pw_s[pr][scol] = pk;
        }
        __syncthreads();

        // ---- MFMA: content (qc) + skewed positional (qc + (pb-cb)) ----
        f32x4 Sc[4], G[5];
#pragma unroll
        for (int nt = 0; nt < 4; ++nt) Sc[nt] = (f32x4){0.f, 0.f, 0.f, 0.f};
#pragma unroll
        for (int ct = 0; ct < 5; ++ct) G[ct] = (f32x4){0.f, 0.f, 0.f, 0.f};
#pragma unroll
        for (int kc = 0; kc < 2; ++kc) {
            short8 ac = *(const short8*)&qc_s[16 * w + n16][kc * 32 + quad * 8];
            short8 ap;
            const unsigned short* acp = (const unsigned short*)&ac;
            unsigned short* app = (unsigned short*)&ap;
#pragma unroll
            for (int e = 0; e < 8; ++e)
                app[e] = fbits(bits2f(acp[e]) + dl[kc][e]);
#pragma unroll
            for (int nt = 0; nt < 4; ++nt) {
                short8 bk = *(const short8*)&k_s[nt * 16 + n16][kc * 32 + quad * 8];
                Sc[nt] = MFMA16(ac, bk, Sc[nt]);
            }
#pragma unroll
            for (int ct = 0; ct < 5; ++ct) {
                short8 bp = *(const short8*)&pw_s[pwoff + ct * 16 + n16][kc * 32 + quad * 8];
                G[ct] = MFMA16(ap, bp, G[ct]);
            }
        }
#pragma unroll
        for (int ct = 0; ct < 5; ++ct)
#pragma unroll
            for (int r = 0; r < 4; ++r)
                *(bf16*)&gbuf[w][quad * 4 + r][ct * 16 + n16] = f2b(G[ct][r]);
        __syncthreads();

        // ---- assemble scores (base-2 domain), online softmax ----
        float sreg[4][4];
#pragma unroll
        for (int ct = 0; ct < 4; ++ct) {
#pragma unroll
            for (int r = 0; r < 4; ++r) {
                int ii = quad * 4 + r;
                int c  = ct * 16 + n16 - ii + 15;   // 0..78
                sreg[ct][r] = (Sc[ct][r] + bits2f(gbuf[w][ii][c])) * sc_scale;
            }
        }
        if (i0 == 0 && w == 0 && j0 == 960 && lane == 15)   // wrap (i=0, j=T-1)
            sreg[3][0] = (Sc[3][0] + wrap_s) * sc_scale;

        float rowsum[4], alpha[4];
#pragma unroll
        for (int r = 0; r < 4; ++r) {
            float m = fmaxf(fmaxf(sreg[0][r], sreg[1][r]), fmaxf(sreg[2][r], sreg[3][r]));
#pragma unroll
            for (int msk = 1; msk < 16; msk <<= 1) m = fmaxf(m, __shfl_xor(m, msk, 64));
            float mn = fmaxf(mrow[r], m);
            alpha[r] = exp2f(mrow[r] - mn);
            mrow[r] = mn;
            float rs = 0.f;
#pragma unroll
            for (int ct = 0; ct < 4; ++ct) {
                float pe = exp2f(sreg[ct][r] - mn);
                sreg[ct][r] = pe;
                rs += pe;
            }
#pragma unroll
            for (int msk = 1; msk < 16; msk <<= 1) rs += __shfl_xor(rs, msk, 64);
            rowsum[r] = rs;
        }
#pragma unroll
        for (int r = 0; r < 4; ++r) {
            lrow[r] = lrow[r] * alpha[r] + rowsum[r];
#pragma unroll
            for (int nt = 0; nt < 4; ++nt) O[nt][r] *= alpha[r];
        }
        // P -> LDS (reuse pw_s rows [16w,16w+16)) to re-enter as A-fragments
#pragma unroll
        for (int ct = 0; ct < 4; ++ct)
#pragma unroll
            for (int r = 0; r < 4; ++r)
                *(bf16*)&pw_s[16 * w + quad * 4 + r][ct * 16 + n16] = f2b(sreg[ct][r]);

        // ---- PV ----
#pragma unroll
        for (int kc = 0; kc < 2; ++kc) {
            short8 pa = *(const short8*)&pw_s[16 * w + n16][kc * 32 + quad * 8];
#pragma unroll
            for (int nt = 0; nt < 4; ++nt) {
                short8 vb = *(const short8*)&vt_s[nt * 16 + n16][kc * 32 + quad * 8];
                O[nt] = MFMA16(pa, vb, O[nt]);
            }
        }
    }

#pragma unroll
    for (int r = 0; r < 4; ++r) {
        float inv = 1.f / lrow[r];
        int row = i0 + 16 * w + quad * 4 + r;
#pragma unroll
        for (int nt = 0; nt < 4; ++nt)
            o[(size_t)(b * T_ + row) * 512 + h64 + nt * 16 + n16] = f2b(O[nt][r] * inv);
    }
}

extern "C" void kernel_launch(void* const* d_in, const int* in_sizes, int n_in,
                              void* d_out, int out_size, void* d_ws, size_t ws_size,
                              hipStream_t stream) {
    (void)in_sizes; (void)n_in; (void)out_size;
    const float* x     = (const float*)d_in[0];
    const float* pos   = (const float*)d_in[1];
    const float* cb    = (const float*)d_in[2];
    const float* pb    = (const float*)d_in[3];
    const float* gamma = (const float*)d_in[4];
    const float* beta  = (const float*)d_in[5];
    const float* Wq    = (const float*)d_in[6];
    const float* bq    = (const float*)d_in[7];
    const float* Wk    = (const float*)d_in[8];
    const float* bk    = (const float*)d_in[9];
    const float* Wv    = (const float*)d_in[10];
    const float* bv    = (const float*)d_in[11];
    const float* Wp    = (const float*)d_in[12];
    const float* Wo    = (const float*)d_in[13];
    const float* bo    = (const float*)d_in[14];
    float* out = (float*)d_out;

    const int BT = B_ * T_;       // 4096
    const int BL = B_ * L_;       // 8188

    const size_t sz_bt = (size_t)BT * D_;      // 2,097,152
    const size_t sz_bl = (size_t)BL * D_;      // 4,192,256
    const size_t sz_w  = 512 * 512;            // 262,144
    const size_t need  = (5 * sz_bt + sz_bl + 5 * sz_w) * sizeof(bf16) + 1536 * sizeof(float);
    if (ws_size < need) return;

    // layout: y | o | q | k | v | p | Wqkv_t | Wp_t | Wo_t | biasq
    // pos_bf aliases y∪o (2*sz_bt = 4,194,304 elems >= 8192 rows x 512): y dead after
    // qkv-GEMM, o written by attn only after p-GEMM consumed pos_bf.
    bf16* y       = (bf16*)d_ws;
    bf16* o       = y + sz_bt;
    bf16* q       = y + 2 * sz_bt;
    bf16* k       = y + 3 * sz_bt;
    bf16* v       = y + 4 * sz_bt;
    bf16* p       = y + 5 * sz_bt;
    bf16* Wqkv_t  = p + sz_bl;
    bf16* Wp_t    = Wqkv_t + 3 * sz_w;
    bf16* Wo_t    = Wp_t + sz_w;
    float* biasq  = (float*)(Wo_t + sz_w);
    bf16* pos_bf  = y;

    prep_weights<<<dim3(16, 16, 5), dim3(32, 8), 0, stream>>>(Wq, Wk, Wv, Wp, Wo,
                                                              Wqkv_t, Wp_t, Wo_t);
    concat_bias<<<6, 256, 0, stream>>>(bq, bk, bv, biasq);
    lnorm_kernel<<<BT, 256, 0, stream>>>(x, gamma, beta, y);

    // q|k|v fused: [4096,512] x [512,1536]
    gemm_mfma<false><<<dim3(12, 32), 256, 0, stream>>>(y, Wqkv_t, biasq, nullptr, q, BT, sz_bt);
    // pos -> bf16 (over dead y|o region), then p: [8188,512] x [512,512]
    pos_cvt<<<2047, 256, 0, stream>>>(pos, pos_bf);
    gemm_mfma<false><<<dim3(4, 64), 256, 0, stream>>>(pos_bf, Wp_t, nullptr, nullptr, p, BL, 0);

    attn_mfma_kernel<<<dim3(T_ / 64, H_, B_), 256, 0, stream>>>(q, k, v, p, cb, pb, o);

    // out: [4096,512] x [512,512] + bo + x residual -> f32 d_out
    gemm_mfma<true><<<dim3(4, 32), 256, 0, stream>>>(o, Wo_t, bo, x, out, BT, 0);
}

// Round 7
// 233.081 us; speedup vs baseline: 13.3595x; 1.1340x over previous
//
#include <hip/hip_runtime.h>
#include <hip/hip_bf16.h>

typedef __hip_bfloat16 bf16;
typedef __attribute__((ext_vector_type(8))) short short8;
typedef __attribute__((ext_vector_type(4))) float f32x4;

#define B_  4
#define T_  1024
#define D_  512
#define H_  8
#define DK_ 64
#define L_  2047   // 2*T - 1

__device__ __forceinline__ float b2f(bf16 v) { return __bfloat162float(v); }
__device__ __forceinline__ bf16  f2b(float v) { return __float2bfloat16(v); }
__device__ __forceinline__ float bits2f(unsigned short u) {
    return __uint_as_float(((unsigned int)u) << 16);
}
__device__ __forceinline__ unsigned short fbits(float v) {
    bf16 h = f2b(v); return *(unsigned short*)&h;
}

#define MFMA16(a, b, c) __builtin_amdgcn_mfma_f32_16x16x32_bf16(a, b, c, 0, 0, 0)
#define GLD_LDS16(g, l) __builtin_amdgcn_global_load_lds( \
    (const __attribute__((address_space(1))) unsigned int*)(g), \
    (__attribute__((address_space(3))) unsigned int*)(l), 16, 0, 0)

// ============ prep_all: weight transpose + bias concat + pos cvt + layernorm ============
// flat grid: [0,1280) weights, [1280,1286) bias, [1286,3333) pos_cvt, [3333,7429) lnorm
__global__ __launch_bounds__(256) void prep_all(
        const float* __restrict__ Wq, const float* __restrict__ Wk,
        const float* __restrict__ Wv, const float* __restrict__ Wp,
        const float* __restrict__ Wo,
        const float* __restrict__ bq, const float* __restrict__ bk,
        const float* __restrict__ bv,
        const float* __restrict__ pos, const float* __restrict__ x,
        const float* __restrict__ gamma, const float* __restrict__ beta,
        bf16* __restrict__ Wqkv_t, bf16* __restrict__ Wp_t, bf16* __restrict__ Wo_t,
        float* __restrict__ biasq, bf16* __restrict__ pos_bf, bf16* __restrict__ y) {
    __shared__ float tl[32][33];
    __shared__ float ws1[4], ws2[4];
    const int blk = blockIdx.x;
    const int t = threadIdx.x;

    if (blk < 1280) {            // ---- weight transpose: f32 [k][n] -> bf16 [n][k] ----
        const int z = blk >> 8, rem = blk & 255;
        const float* W; bf16* Wt; int roff;
        switch (z) {
            case 0: W = Wq; Wt = Wqkv_t; roff = 0;    break;
            case 1: W = Wk; Wt = Wqkv_t; roff = 512;  break;
            case 2: W = Wv; Wt = Wqkv_t; roff = 1024; break;
            case 3: W = Wp; Wt = Wp_t;   roff = 0;    break;
            default: W = Wo; Wt = Wo_t;  roff = 0;    break;
        }
        const int n0 = (rem & 15) * 32, k0 = (rem >> 4) * 32;
        const int tx = t & 31, ty = t >> 5;
#pragma unroll
        for (int r = 0; r < 4; ++r)
            tl[ty + r * 8][tx] = W[(size_t)(k0 + ty + r * 8) * 512 + n0 + tx];
        __syncthreads();
#pragma unroll
        for (int r = 0; r < 4; ++r)
            Wt[(size_t)(roff + n0 + ty + r * 8) * 512 + k0 + tx] = f2b(tl[tx][ty + r * 8]);
    } else if (blk < 1286) {     // ---- bias concat ----
        int i = (blk - 1280) * 256 + t;
        biasq[i] = (i < 512) ? bq[i] : (i < 1024) ? bk[i - 512] : bv[i - 1024];
    } else if (blk < 3333) {     // ---- pos f32 -> bf16 ----
        size_t i = ((size_t)(blk - 1286) * 256 + t) * 8;
        float4 a = *(const float4*)(pos + i);
        float4 c = *(const float4*)(pos + i + 4);
        uint4 wv;
        wv.x = ((unsigned)fbits(a.y) << 16) | fbits(a.x);
        wv.y = ((unsigned)fbits(a.w) << 16) | fbits(a.z);
        wv.z = ((unsigned)fbits(c.y) << 16) | fbits(c.x);
        wv.w = ((unsigned)fbits(c.w) << 16) | fbits(c.z);
        *(uint4*)((unsigned short*)pos_bf + i) = wv;
    } else {                     // ---- layernorm row ----
        const int row = blk - 3333;
        const float* xr = x + (size_t)row * D_;
        float v0 = xr[t];
        float v1 = xr[t + 256];
        float s  = v0 + v1;
        float s2 = v0 * v0 + v1 * v1;
#pragma unroll
        for (int off = 32; off > 0; off >>= 1) {
            s  += __shfl_down(s,  off, 64);
            s2 += __shfl_down(s2, off, 64);
        }
        const int wid = t >> 6, lane = t & 63;
        if (!lane) { ws1[wid] = s; ws2[wid] = s2; }
        __syncthreads();
        float S  = ws1[0] + ws1[1] + ws1[2] + ws1[3];
        float S2 = ws2[0] + ws2[1] + ws2[2] + ws2[3];
        float mean = S * (1.f / D_);
        float var  = S2 * (1.f / D_) - mean * mean;
        float r = rsqrtf(var + 1e-3f);
        bf16* yr = y + (size_t)row * D_;
        yr[t]       = f2b((v0 - mean) * r * gamma[t]       + beta[t]);
        yr[t + 256] = f2b((v1 - mean) * r * gamma[t + 256] + beta[t + 256]);
    }
}

// ============ MFMA GEMM body: [M,512] x Wt^T (Wt: [N][512] bf16) ============
// 128x128 tile, BK=32, 256 thr = 2x2 waves, each wave 64x64 via 4x4 mfma16x16x32.
template <bool C_F32>
__device__ __forceinline__ void gemm_body(
        const bf16* __restrict__ A, const bf16* __restrict__ Wt,
        const float* __restrict__ bias, const float* __restrict__ resid,
        void* __restrict__ Cv, int M, size_t seg_elems, int m0, int n0,
        unsigned short (*A_s)[32], unsigned short (*B_s)[32]) {
    const int t = threadIdx.x;
    const int w = t >> 6, lane = t & 63;
    const int quad = lane >> 4, n16 = lane & 15;
    const int wm = (w >> 1) * 64, wn = (w & 1) * 64;

    f32x4 acc[4][4];
#pragma unroll
    for (int a = 0; a < 4; ++a)
#pragma unroll
        for (int b = 0; b < 4; ++b) acc[a][b] = (f32x4){0.f, 0.f, 0.f, 0.f};

    for (int k0 = 0; k0 < 512; k0 += 32) {
        __syncthreads();
#pragma unroll
        for (int ps = 0; ps < 2; ++ps) {
            int br = (ps * 4 + w) * 16;
            const bf16* gp = A + (size_t)(m0 + br + (lane >> 2)) * 512 + k0 + (lane & 3) * 8;
            GLD_LDS16(gp, &A_s[br][0]);
        }
#pragma unroll
        for (int ps = 0; ps < 2; ++ps) {
            int br = (ps * 4 + w) * 16;
            const bf16* gp = Wt + (size_t)(n0 + br + (lane >> 2)) * 512 + k0 + (lane & 3) * 8;
            GLD_LDS16(gp, &B_s[br][0]);
        }
        __syncthreads();

        short8 af[4], bfr[4];
#pragma unroll
        for (int i = 0; i < 4; ++i) {
            af[i]  = *(const short8*)&A_s[wm + i * 16 + n16][quad * 8];
            bfr[i] = *(const short8*)&B_s[wn + i * 16 + n16][quad * 8];
        }
#pragma unroll
        for (int mi = 0; mi < 4; ++mi)
#pragma unroll
            for (int ni = 0; ni < 4; ++ni)
                acc[mi][ni] = MFMA16(af[mi], bfr[ni], acc[mi][ni]);
    }

    const int seg = n0 >> 9;
#pragma unroll
    for (int mi = 0; mi < 4; ++mi) {
#pragma unroll
        for (int r = 0; r < 4; ++r) {
            int row = m0 + wm + mi * 16 + quad * 4 + r;
            if (row >= M) continue;
#pragma unroll
            for (int ni = 0; ni < 4; ++ni) {
                int col  = n0 + wn + ni * 16 + n16;
                int coll = col & 511;
                float vv = acc[mi][ni][r];
                if (bias) vv += bias[col];
                if constexpr (C_F32) {
                    float* C = (float*)Cv + seg * seg_elems;
                    if (resid) vv += resid[(size_t)row * 512 + coll];
                    C[(size_t)row * 512 + coll] = vv;
                } else {
                    bf16* C = (bf16*)Cv + seg * seg_elems;
                    C[(size_t)row * 512 + coll] = f2b(vv);
                }
            }
        }
    }
}

// qkv GEMM (384 blocks) + p GEMM (256 blocks) in one launch
__global__ __launch_bounds__(256) void gemm_qkvp(
        const bf16* __restrict__ y, const bf16* __restrict__ pos_bf,
        const bf16* __restrict__ Wqkv_t, const bf16* __restrict__ Wp_t,
        const float* __restrict__ biasq,
        bf16* __restrict__ q, bf16* __restrict__ p, size_t seg_elems) {
    __shared__ __align__(16) unsigned short A_s[128][32];
    __shared__ __align__(16) unsigned short B_s[128][32];
    const int gid = blockIdx.x;
    if (gid < 384) {
        int m0 = (gid / 12) * 128, n0 = (gid % 12) * 128;
        gemm_body<false>(y, Wqkv_t, biasq, nullptr, q, 4096, seg_elems, m0, n0, A_s, B_s);
    } else {
        int g2 = gid - 384;
        int m0 = (g2 >> 2) * 128, n0 = (g2 & 3) * 128;
        gemm_body<false>(pos_bf, Wp_t, nullptr, nullptr, p, 8188, 0, m0, n0, A_s, B_s);
    }
}

__global__ __launch_bounds__(256) void gemm_out(
        const bf16* __restrict__ o, const bf16* __restrict__ Wo_t,
        const float* __restrict__ bo, const float* __restrict__ x,
        float* __restrict__ out) {
    __shared__ __align__(16) unsigned short A_s[128][32];
    __shared__ __align__(16) unsigned short B_s[128][32];
    int m0 = (blockIdx.x >> 2) * 128, n0 = (blockIdx.x & 3) * 128;
    gemm_body<true>(o, Wo_t, bo, x, out, 4096, 0, m0, n0, A_s, B_s);
}

// ============ Fused MFMA flash attention ============
// Block = (i-tile of 64 q rows, h, b); wave w owns q rows [i0+16w, i0+16w+16).
// q-fragments (content ac = q+cb, positional ap = q+pb) hoisted to registers.
// K/V/P register-prefetched one tile ahead. scores * (1/8); base-2 softmax.
// wrap element (i=0,j=T-1): positional = (q_1+pb)·p_0, patched scalar.
__global__ __launch_bounds__(256) void attn_mfma_kernel(
        const bf16* __restrict__ q, const bf16* __restrict__ k,
        const bf16* __restrict__ v, const bf16* __restrict__ p,
        const float* __restrict__ cbias, const float* __restrict__ pbias,
        bf16* __restrict__ o) {
    __shared__ __align__(16) unsigned short k_s[64][72];
    __shared__ __align__(16) unsigned short vt_s[64][72];
    __shared__ __align__(16) unsigned short pw_s[128][72];
    __shared__ unsigned short gbuf[4][16][84];   // stride 84: writes {0,8,16,24}, reads {0,6,12,18}
    __shared__ float cb_s[64], pb_s[64];
    __shared__ float wrap_s;

    const int i0 = blockIdx.x * 64;
    const int h  = blockIdx.y;
    const int b  = blockIdx.z;
    const int t  = threadIdx.x;
    const int w    = t >> 6;
    const int lane = t & 63;
    const int quad = lane >> 4;
    const int n16  = lane & 15;
    const int h64  = h * 64;

    if (t < 64)            cb_s[t]      = cbias[h64 + t];
    else if (t < 128)      pb_s[t - 64] = pbias[h64 + t - 64];
    __syncthreads();

    // ---- hoisted q-fragments: ac = q+cb, ap = q+pb (loop-invariant) ----
    short8 ac[2], ap[2];
    {
        const unsigned short* qrow = (const unsigned short*)q +
            ((size_t)(b * T_ + i0 + 16 * w + n16) * 512 + h64);
#pragma unroll
        for (int kc = 0; kc < 2; ++kc) {
            uint4 u = *(const uint4*)(qrow + kc * 32 + quad * 8);
            const unsigned short* uv = (const unsigned short*)&u;
            unsigned short* acp = (unsigned short*)&ac[kc];
            unsigned short* app = (unsigned short*)&ap[kc];
#pragma unroll
            for (int e = 0; e < 8; ++e) {
                int d = kc * 32 + quad * 8 + e;
                float qv = bits2f(uv[e]);
                acp[e] = fbits(qv + cb_s[d]);
                app[e] = fbits(qv + pb_s[d]);
            }
        }
    }
    if (i0 == 0 && t < 64) {   // wrap positional: (q_1 + pb)·p_0
        float part = (b2f(q[(size_t)(b * T_ + 1) * 512 + h64 + t]) + pb_s[t]) *
                     b2f(p[(size_t)(b * L_) * 512 + h64 + t]);
#pragma unroll
        for (int m = 1; m < 64; m <<= 1) part += __shfl_xor(part, m, 64);
        if (t == 0) wrap_s = part;
    }

    float mrow[4], lrow[4];
    f32x4 O[4];
#pragma unroll
    for (int r = 0; r < 4; ++r) { mrow[r] = -1e30f; lrow[r] = 0.f; }
#pragma unroll
    for (int nt = 0; nt < 4; ++nt) O[nt] = (f32x4){0.f, 0.f, 0.f, 0.f};

    const int pwoff = 48 - 16 * w;
    const float sc_scale = 0.125f * 1.4426950408889634f;   // (1/8)·log2(e)

    const int srow = t >> 3;           // 0..31
    const int scol = (t & 7) * 8;      // 0..56
    const int vd2  = (t & 31) * 2;
    const int vjg  = t >> 5;

    uint4 kReg[2]; unsigned int vReg[8]; uint4 pReg[4];
    auto prefetch = [&](int j0) {
#pragma unroll
        for (int ps = 0; ps < 2; ++ps)
            kReg[ps] = *(const uint4*)((const unsigned short*)k +
                       ((size_t)(b * T_ + j0 + srow + ps * 32) * 512 + h64 + scol));
        const unsigned short* vg = (const unsigned short*)v +
            ((size_t)(b * T_ + j0 + vjg * 8) * 512 + h64 + vd2);
#pragma unroll
        for (int e = 0; e < 8; ++e) vReg[e] = *(const unsigned int*)(vg + (size_t)e * 512);
        const int sl_base = T_ - i0 - 63 + j0;
#pragma unroll
        for (int ps = 0; ps < 4; ++ps) {
            int sl = sl_base + srow + ps * 32;
            pReg[ps] = (uint4){0u, 0u, 0u, 0u};
            if (sl < L_)
                pReg[ps] = *(const uint4*)((const unsigned short*)p +
                           ((size_t)(b * L_ + sl) * 512 + h64 + scol));
        }
    };
    prefetch(0);

    for (int j0 = 0; j0 < T_; j0 += 64) {
        __syncthreads();   // prior iteration's LDS consumers done

        // ---- regs -> LDS ----
#pragma unroll
        for (int ps = 0; ps < 2; ++ps)
            *(uint4*)&k_s[srow + ps * 32][scol] = kReg[ps];
        {
            uint4 wlo, whi;
            wlo.x = (vReg[0] & 0xffffu) | (vReg[1] << 16);
            wlo.y = (vReg[2] & 0xffffu) | (vReg[3] << 16);
            wlo.z = (vReg[4] & 0xffffu) | (vReg[5] << 16);
            wlo.w = (vReg[6] & 0xffffu) | (vReg[7] << 16);
            whi.x = (vReg[0] >> 16) | (vReg[1] & 0xffff0000u);
            whi.y = (vReg[2] >> 16) | (vReg[3] & 0xffff0000u);
            whi.z = (vReg[4] >> 16) | (vReg[5] & 0xffff0000u);
            whi.w = (vReg[6] >> 16) | (vReg[7] & 0xffff0000u);
            *(uint4*)&vt_s[vd2][vjg * 8]     = wlo;
            *(uint4*)&vt_s[vd2 + 1][vjg * 8] = whi;
        }
#pragma unroll
        for (int ps = 0; ps < 4; ++ps)
            *(uint4*)&pw_s[srow + ps * 32][scol] = pReg[ps];
        __syncthreads();

        if (j0 + 64 < T_) prefetch(j0 + 64);   // overlap with compute below

        // ---- MFMA: content (ac·K) + skewed positional (ap·P) ----
        f32x4 Sc[4], G[5];
#pragma unroll
        for (int nt = 0; nt < 4; ++nt) Sc[nt] = (f32x4){0.f, 0.f, 0.f, 0.f};
#pragma unroll
        for (int ct = 0; ct < 5; ++ct) G[ct] = (f32x4){0.f, 0.f, 0.f, 0.f};
#pragma unroll
        for (int kc = 0; kc < 2; ++kc) {
#pragma unroll
            for (int nt = 0; nt < 4; ++nt) {
                short8 bk = *(const short8*)&k_s[nt * 16 + n16][kc * 32 + quad * 8];
                Sc[nt] = MFMA16(ac[kc], bk, Sc[nt]);
            }
#pragma unroll
            for (int ct = 0; ct < 5; ++ct) {
                short8 bp = *(const short8*)&pw_s[pwoff + ct * 16 + n16][kc * 32 + quad * 8];
                G[ct] = MFMA16(ap[kc], bp, G[ct]);
            }
        }
#pragma unroll
        for (int ct = 0; ct < 5; ++ct)
#pragma unroll
            for (int r = 0; r < 4; ++r)
                *(bf16*)&gbuf[w][quad * 4 + r][ct * 16 + n16] = f2b(G[ct][r]);
        __syncthreads();

        // ---- assemble scores (base-2 domain), online softmax ----
        float sreg[4][4];
#pragma unroll
        for (int ct = 0; ct < 4; ++ct) {
#pragma unroll
            for (int r = 0; r < 4; ++r) {
                int ii = quad * 4 + r;
                int c  = ct * 16 + n16 - ii + 15;   // 0..78
                sreg[ct][r] = (Sc[ct][r] + bits2f(gbuf[w][ii][c])) * sc_scale;
            }
        }
        if (i0 == 0 && w == 0 && j0 == 960 && lane == 15)   // wrap (i=0, j=T-1)
            sreg[3][0] = (Sc[3][0] + wrap_s) * sc_scale;

        float rowsum[4], alpha[4];
#pragma unroll
        for (int r = 0; r < 4; ++r) {
            float m = fmaxf(fmaxf(sreg[0][r], sreg[1][r]), fmaxf(sreg[2][r], sreg[3][r]));
#pragma unroll
            for (int msk = 1; msk < 16; msk <<= 1) m = fmaxf(m, __shfl_xor(m, msk, 64));
            float mn = fmaxf(mrow[r], m);
            alpha[r] = exp2f(mrow[r] - mn);
            mrow[r] = mn;
            float rs = 0.f;
#pragma unroll
            for (int ct = 0; ct < 4; ++ct) {
                float pe = exp2f(sreg[ct][r] - mn);
                sreg[ct][r] = pe;
                rs += pe;
            }
#pragma unroll
            for (int msk = 1; msk < 16; msk <<= 1) rs += __shfl_xor(rs, msk, 64);
            rowsum[r] = rs;
        }
#pragma unroll
        for (int r = 0; r < 4; ++r) {
            lrow[r] = lrow[r] * alpha[r] + rowsum[r];
#pragma unroll
            for (int nt = 0; nt < 4; ++nt) O[nt][r] *= alpha[r];
        }
        // P -> LDS (reuse pw_s rows [16w,16w+16)) to re-enter as A-fragments
#pragma unroll
        for (int ct = 0; ct < 4; ++ct)
#pragma unroll
            for (int r = 0; r < 4; ++r)
                *(bf16*)&pw_s[16 * w + quad * 4 + r][ct * 16 + n16] = f2b(sreg[ct][r]);

        // ---- PV ----
#pragma unroll
        for (int kc = 0; kc < 2; ++kc) {
            short8 pa = *(const short8*)&pw_s[16 * w + n16][kc * 32 + quad * 8];
#pragma unroll
            for (int nt = 0; nt < 4; ++nt) {
                short8 vb = *(const short8*)&vt_s[nt * 16 + n16][kc * 32 + quad * 8];
                O[nt] = MFMA16(pa, vb, O[nt]);
            }
        }
    }

#pragma unroll
    for (int r = 0; r < 4; ++r) {
        float inv = 1.f / lrow[r];
        int row = i0 + 16 * w + quad * 4 + r;
#pragma unroll
        for (int nt = 0; nt < 4; ++nt)
            o[(size_t)(b * T_ + row) * 512 + h64 + nt * 16 + n16] = f2b(O[nt][r] * inv);
    }
}

extern "C" void kernel_launch(void* const* d_in, const int* in_sizes, int n_in,
                              void* d_out, int out_size, void* d_ws, size_t ws_size,
                              hipStream_t stream) {
    (void)in_sizes; (void)n_in; (void)out_size;
    const float* x     = (const float*)d_in[0];
    const float* pos   = (const float*)d_in[1];
    const float* cb    = (const float*)d_in[2];
    const float* pb    = (const float*)d_in[3];
    const float* gamma = (const float*)d_in[4];
    const float* beta  = (const float*)d_in[5];
    const float* Wq    = (const float*)d_in[6];
    const float* bq    = (const float*)d_in[7];
    const float* Wk    = (const float*)d_in[8];
    const float* bk    = (const float*)d_in[9];
    const float* Wv    = (const float*)d_in[10];
    const float* bv    = (const float*)d_in[11];
    const float* Wp    = (const float*)d_in[12];
    const float* Wo    = (const float*)d_in[13];
    const float* bo    = (const float*)d_in[14];
    float* out = (float*)d_out;

    const int BT = B_ * T_;       // 4096

    const size_t sz_bt = (size_t)BT * D_;            // 2,097,152
    const size_t sz_bl = (size_t)(B_ * L_) * D_;     // 4,192,256
    const size_t sz_w  = 512 * 512;
    const size_t need  = (5 * sz_bt + sz_bl + 5 * sz_w) * sizeof(bf16) + 1536 * sizeof(float);
    if (ws_size < need) return;

    // ws layout: y | o | q | k | v | p | Wqkv_t | Wp_t | Wo_t | biasq
    bf16* y       = (bf16*)d_ws;
    bf16* o       = y + sz_bt;
    bf16* q       = y + 2 * sz_bt;
    bf16* k       = y + 3 * sz_bt;
    bf16* v       = y + 4 * sz_bt;
    bf16* p       = y + 5 * sz_bt;
    bf16* Wqkv_t  = p + sz_bl;
    bf16* Wp_t    = Wqkv_t + 3 * sz_w;
    bf16* Wo_t    = Wp_t + sz_w;
    float* biasq  = (float*)(Wo_t + sz_w);
    // pos_bf scratch lives in d_out (8.39 MB f32 >= 8188*512 bf16 = 8.38 MB);
    // gemm_out later overwrites every element of d_out.
    bf16* pos_bf  = (bf16*)d_out;

    prep_all<<<7429, 256, 0, stream>>>(Wq, Wk, Wv, Wp, Wo, bq, bk, bv, pos, x,
                                       gamma, beta, Wqkv_t, Wp_t, Wo_t, biasq, pos_bf, y);

    // qkv: [4096,512]x[512,1536] (384 blocks) + p: [8188,512]x[512,512] (256 blocks)
    gemm_qkvp<<<640, 256, 0, stream>>>(y, pos_bf, Wqkv_t, Wp_t, biasq, q, p, sz_bt);

    attn_mfma_kernel<<<dim3(T_ / 64, H_, B_), 256, 0, stream>>>(q, k, v, p, cb, pb, o);

    // out: [4096,512]x[512,512] + bo + x residual -> f32 d_out
    gemm_out<<<128, 256, 0, stream>>>(o, Wo_t, bo, x, out);
}

// Round 8
// 232.347 us; speedup vs baseline: 13.4017x; 1.0032x over previous
//
#include <hip/hip_runtime.h>
#include <hip/hip_bf16.h>

typedef __hip_bfloat16 bf16;
typedef __attribute__((ext_vector_type(8))) short short8;
typedef __attribute__((ext_vector_type(4))) float f32x4;

#define B_  4
#define T_  1024
#define D_  512
#define H_  8
#define DK_ 64
#define L_  2047   // 2*T - 1

__device__ __forceinline__ float b2f(bf16 v) { return __bfloat162float(v); }
__device__ __forceinline__ bf16  f2b(float v) { return __float2bfloat16(v); }
__device__ __forceinline__ float bits2f(unsigned short u) {
    return __uint_as_float(((unsigned int)u) << 16);
}
__device__ __forceinline__ unsigned short fbits(float v) {
    bf16 h = f2b(v); return *(unsigned short*)&h;
}

#define MFMA16(a, b, c) __builtin_amdgcn_mfma_f32_16x16x32_bf16(a, b, c, 0, 0, 0)
#define GLD_LDS16(g, l) __builtin_amdgcn_global_load_lds( \
    (const __attribute__((address_space(1))) unsigned int*)(g), \
    (__attribute__((address_space(3))) unsigned int*)(l), 16, 0, 0)

// ============ prep_all: weight transpose + bias concat + pos cvt + layernorm ============
// flat grid: [0,1280) weights, [1280,1286) bias, [1286,3333) pos_cvt, [3333,7429) lnorm
__global__ __launch_bounds__(256) void prep_all(
        const float* __restrict__ Wq, const float* __restrict__ Wk,
        const float* __restrict__ Wv, const float* __restrict__ Wp,
        const float* __restrict__ Wo,
        const float* __restrict__ bq, const float* __restrict__ bk,
        const float* __restrict__ bv,
        const float* __restrict__ pos, const float* __restrict__ x,
        const float* __restrict__ gamma, const float* __restrict__ beta,
        bf16* __restrict__ Wqkv_t, bf16* __restrict__ Wp_t, bf16* __restrict__ Wo_t,
        float* __restrict__ biasq, bf16* __restrict__ pos_bf, bf16* __restrict__ y) {
    __shared__ float tl[32][33];
    __shared__ float ws1[4], ws2[4];
    const int blk = blockIdx.x;
    const int t = threadIdx.x;

    if (blk < 1280) {            // ---- weight transpose: f32 [k][n] -> bf16 [n][k] ----
        const int z = blk >> 8, rem = blk & 255;
        const float* W; bf16* Wt; int roff;
        switch (z) {
            case 0: W = Wq; Wt = Wqkv_t; roff = 0;    break;
            case 1: W = Wk; Wt = Wqkv_t; roff = 512;  break;
            case 2: W = Wv; Wt = Wqkv_t; roff = 1024; break;
            case 3: W = Wp; Wt = Wp_t;   roff = 0;    break;
            default: W = Wo; Wt = Wo_t;  roff = 0;    break;
        }
        const int n0 = (rem & 15) * 32, k0 = (rem >> 4) * 32;
        const int tx = t & 31, ty = t >> 5;
#pragma unroll
        for (int r = 0; r < 4; ++r)
            tl[ty + r * 8][tx] = W[(size_t)(k0 + ty + r * 8) * 512 + n0 + tx];
        __syncthreads();
#pragma unroll
        for (int r = 0; r < 4; ++r)
            Wt[(size_t)(roff + n0 + ty + r * 8) * 512 + k0 + tx] = f2b(tl[tx][ty + r * 8]);
    } else if (blk < 1286) {     // ---- bias concat ----
        int i = (blk - 1280) * 256 + t;
        biasq[i] = (i < 512) ? bq[i] : (i < 1024) ? bk[i - 512] : bv[i - 1024];
    } else if (blk < 3333) {     // ---- pos f32 -> bf16 ----
        size_t i = ((size_t)(blk - 1286) * 256 + t) * 8;
        float4 a = *(const float4*)(pos + i);
        float4 c = *(const float4*)(pos + i + 4);
        uint4 wv;
        wv.x = ((unsigned)fbits(a.y) << 16) | fbits(a.x);
        wv.y = ((unsigned)fbits(a.w) << 16) | fbits(a.z);
        wv.z = ((unsigned)fbits(c.y) << 16) | fbits(c.x);
        wv.w = ((unsigned)fbits(c.w) << 16) | fbits(c.z);
        *(uint4*)((unsigned short*)pos_bf + i) = wv;
    } else {                     // ---- layernorm row ----
        const int row = blk - 3333;
        const float* xr = x + (size_t)row * D_;
        float v0 = xr[t];
        float v1 = xr[t + 256];
        float s  = v0 + v1;
        float s2 = v0 * v0 + v1 * v1;
#pragma unroll
        for (int off = 32; off > 0; off >>= 1) {
            s  += __shfl_down(s,  off, 64);
            s2 += __shfl_down(s2, off, 64);
        }
        const int wid = t >> 6, lane = t & 63;
        if (!lane) { ws1[wid] = s; ws2[wid] = s2; }
        __syncthreads();
        float S  = ws1[0] + ws1[1] + ws1[2] + ws1[3];
        float S2 = ws2[0] + ws2[1] + ws2[2] + ws2[3];
        float mean = S * (1.f / D_);
        float var  = S2 * (1.f / D_) - mean * mean;
        float r = rsqrtf(var + 1e-3f);
        bf16* yr = y + (size_t)row * D_;
        yr[t]       = f2b((v0 - mean) * r * gamma[t]       + beta[t]);
        yr[t + 256] = f2b((v1 - mean) * r * gamma[t + 256] + beta[t + 256]);
    }
}

// ============ MFMA GEMM body: [M,512] x Wt^T (Wt: [N][512] bf16) ============
// 128x128 tile, BK=32, double-buffered LDS: next-K global_load_lds issued right
// after the barrier so the vmcnt drain at the NEXT barrier finds them complete.
template <bool C_F32>
__device__ __forceinline__ void gemm_body(
        const bf16* __restrict__ A, const bf16* __restrict__ Wt,
        const float* __restrict__ bias, const float* __restrict__ resid,
        void* __restrict__ Cv, int M, size_t seg_elems, int m0, int n0,
        unsigned short (*A_s)[32], unsigned short (*B_s)[32]) {   // [256][32]
    const int t = threadIdx.x;
    const int w = t >> 6, lane = t & 63;
    const int quad = lane >> 4, n16 = lane & 15;
    const int wm = (w >> 1) * 64, wn = (w & 1) * 64;

    f32x4 acc[4][4];
#pragma unroll
    for (int a = 0; a < 4; ++a)
#pragma unroll
        for (int b = 0; b < 4; ++b) acc[a][b] = (f32x4){0.f, 0.f, 0.f, 0.f};

    const int ar = lane >> 2, ac8 = (lane & 3) * 8;
    auto stage = [&](int k0, int buf) {
        const int bo = buf << 7;
#pragma unroll
        for (int ps = 0; ps < 2; ++ps) {
            int br = (ps * 4 + w) * 16;
            GLD_LDS16(A  + (size_t)(m0 + br + ar) * 512 + k0 + ac8, &A_s[bo + br][0]);
            GLD_LDS16(Wt + (size_t)(n0 + br + ar) * 512 + k0 + ac8, &B_s[bo + br][0]);
        }
    };
    stage(0, 0);
    int cur = 0;
    for (int k0 = 0; k0 < 512; k0 += 32) {
        __syncthreads();                    // drains cur loads; cur^1 reads done
        if (k0 + 32 < 512) stage(k0 + 32, cur ^ 1);
        const int bo = cur << 7;
        short8 af[4], bfr[4];
#pragma unroll
        for (int i = 0; i < 4; ++i) {
            af[i]  = *(const short8*)&A_s[bo + wm + i * 16 + n16][quad * 8];
            bfr[i] = *(const short8*)&B_s[bo + wn + i * 16 + n16][quad * 8];
        }
#pragma unroll
        for (int mi = 0; mi < 4; ++mi)
#pragma unroll
            for (int ni = 0; ni < 4; ++ni)
                acc[mi][ni] = MFMA16(af[mi], bfr[ni], acc[mi][ni]);
        cur ^= 1;
    }

    const int seg = n0 >> 9;
#pragma unroll
    for (int mi = 0; mi < 4; ++mi) {
#pragma unroll
        for (int r = 0; r < 4; ++r) {
            int row = m0 + wm + mi * 16 + quad * 4 + r;
            if (row >= M) continue;
#pragma unroll
            for (int ni = 0; ni < 4; ++ni) {
                int col  = n0 + wn + ni * 16 + n16;
                int coll = col & 511;
                float vv = acc[mi][ni][r];
                if (bias) vv += bias[col];
                if constexpr (C_F32) {
                    float* C = (float*)Cv + seg * seg_elems;
                    if (resid) vv += resid[(size_t)row * 512 + coll];
                    C[(size_t)row * 512 + coll] = vv;
                } else {
                    bf16* C = (bf16*)Cv + seg * seg_elems;
                    C[(size_t)row * 512 + coll] = f2b(vv);
                }
            }
        }
    }
}

// qkv GEMM (384 blocks) + p GEMM (256 blocks) in one launch
__global__ __launch_bounds__(256) void gemm_qkvp(
        const bf16* __restrict__ y, const bf16* __restrict__ pos_bf,
        const bf16* __restrict__ Wqkv_t, const bf16* __restrict__ Wp_t,
        const float* __restrict__ biasq,
        bf16* __restrict__ q, bf16* __restrict__ p, size_t seg_elems) {
    __shared__ __align__(16) unsigned short A_s[256][32];
    __shared__ __align__(16) unsigned short B_s[256][32];
    const int gid = blockIdx.x;
    if (gid < 384) {
        int m0 = (gid / 12) * 128, n0 = (gid % 12) * 128;
        gemm_body<false>(y, Wqkv_t, biasq, nullptr, q, 4096, seg_elems, m0, n0, A_s, B_s);
    } else {
        int g2 = gid - 384;
        int m0 = (g2 >> 2) * 128, n0 = (g2 & 3) * 128;
        gemm_body<false>(pos_bf, Wp_t, nullptr, nullptr, p, 8188, 0, m0, n0, A_s, B_s);
    }
}

__global__ __launch_bounds__(256) void gemm_out(
        const bf16* __restrict__ o, const bf16* __restrict__ Wo_t,
        const float* __restrict__ bo, const float* __restrict__ x,
        float* __restrict__ out) {
    __shared__ __align__(16) unsigned short A_s[256][32];
    __shared__ __align__(16) unsigned short B_s[256][32];
    int m0 = (blockIdx.x >> 2) * 128, n0 = (blockIdx.x & 3) * 128;
    gemm_body<true>(o, Wo_t, bo, x, out, 4096, 0, m0, n0, A_s, B_s);
}

// ============ Fused MFMA flash attention ============
// Block = (i-tile of 64 q rows, h, b); wave w owns q rows [i0+16w, i0+16w+16).
// q-fragments hoisted; K/V/P register-prefetched one tile ahead.
// G (skewed positional) AND the P softmax matrix both live in wave-private
// gbuf[w] -> only 2 barriers per j-tile (no cross-wave WAR on pw_s).
__global__ __launch_bounds__(256) void attn_mfma_kernel(
        const bf16* __restrict__ q, const bf16* __restrict__ k,
        const bf16* __restrict__ v, const bf16* __restrict__ p,
        const float* __restrict__ cbias, const float* __restrict__ pbias,
        bf16* __restrict__ o) {
    __shared__ __align__(16) unsigned short k_s[64][72];
    __shared__ __align__(16) unsigned short vt_s[64][72];
    __shared__ __align__(16) unsigned short pw_s[128][72];
    __shared__ __align__(16) unsigned short gbuf[4][16][84];  // G cols 0..79, then P cols 0..63
    __shared__ float cb_s[64], pb_s[64];
    __shared__ float wrap_s;

    const int i0 = blockIdx.x * 64;
    const int h  = blockIdx.y;
    const int b  = blockIdx.z;
    const int t  = threadIdx.x;
    const int w    = t >> 6;
    const int lane = t & 63;
    const int quad = lane >> 4;
    const int n16  = lane & 15;
    const int h64  = h * 64;

    if (t < 64)            cb_s[t]      = cbias[h64 + t];
    else if (t < 128)      pb_s[t - 64] = pbias[h64 + t - 64];
    __syncthreads();

    // ---- hoisted q-fragments: ac = q+cb, ap = q+pb (loop-invariant) ----
    short8 ac[2], ap[2];
    {
        const unsigned short* qrow = (const unsigned short*)q +
            ((size_t)(b * T_ + i0 + 16 * w + n16) * 512 + h64);
#pragma unroll
        for (int kc = 0; kc < 2; ++kc) {
            uint4 u = *(const uint4*)(qrow + kc * 32 + quad * 8);
            const unsigned short* uv = (const unsigned short*)&u;
            unsigned short* acp = (unsigned short*)&ac[kc];
            unsigned short* app = (unsigned short*)&ap[kc];
#pragma unroll
            for (int e = 0; e < 8; ++e) {
                int d = kc * 32 + quad * 8 + e;
                float qv = bits2f(uv[e]);
                acp[e] = fbits(qv + cb_s[d]);
                app[e] = fbits(qv + pb_s[d]);
            }
        }
    }
    if (i0 == 0 && t < 64) {   // wrap positional: (q_1 + pb)·p_0
        float part = (b2f(q[(size_t)(b * T_ + 1) * 512 + h64 + t]) + pb_s[t]) *
                     b2f(p[(size_t)(b * L_) * 512 + h64 + t]);
#pragma unroll
        for (int m = 1; m < 64; m <<= 1) part += __shfl_xor(part, m, 64);
        if (t == 0) wrap_s = part;
    }

    float mrow[4], lrow[4];
    f32x4 O[4];
#pragma unroll
    for (int r = 0; r < 4; ++r) { mrow[r] = -1e30f; lrow[r] = 0.f; }
#pragma unroll
    for (int nt = 0; nt < 4; ++nt) O[nt] = (f32x4){0.f, 0.f, 0.f, 0.f};

    const int pwoff = 48 - 16 * w;
    const float sc_scale = 0.125f * 1.4426950408889634f;   // (1/8)·log2(e)

    const int srow = t >> 3;           // 0..31
    const int scol = (t & 7) * 8;      // 0..56
    const int vd2  = (t & 31) * 2;
    const int vjg  = t >> 5;

    uint4 kReg[2]; unsigned int vReg[8]; uint4 pReg[4];
    auto prefetch = [&](int j0) {
#pragma unroll
        for (int ps = 0; ps < 2; ++ps)
            kReg[ps] = *(const uint4*)((const unsigned short*)k +
                       ((size_t)(b * T_ + j0 + srow + ps * 32) * 512 + h64 + scol));
        const unsigned short* vg = (const unsigned short*)v +
            ((size_t)(b * T_ + j0 + vjg * 8) * 512 + h64 + vd2);
#pragma unroll
        for (int e = 0; e < 8; ++e) vReg[e] = *(const unsigned int*)(vg + (size_t)e * 512);
        const int sl_base = T_ - i0 - 63 + j0;
#pragma unroll
        for (int ps = 0; ps < 4; ++ps) {
            int sl = sl_base + srow + ps * 32;
            pReg[ps] = (uint4){0u, 0u, 0u, 0u};
            if (sl < L_)
                pReg[ps] = *(const uint4*)((const unsigned short*)p +
                           ((size_t)(b * L_ + sl) * 512 + h64 + scol));
        }
    };
    prefetch(0);

    for (int j0 = 0; j0 < T_; j0 += 64) {
        __syncthreads();   // prior tile's k_s/vt_s/pw_s consumers done

        // ---- regs -> LDS ----
#pragma unroll
        for (int ps = 0; ps < 2; ++ps)
            *(uint4*)&k_s[srow + ps * 32][scol] = kReg[ps];
        {
            uint4 wlo, whi;
            wlo.x = (vReg[0] & 0xffffu) | (vReg[1] << 16);
            wlo.y = (vReg[2] & 0xffffu) | (vReg[3] << 16);
            wlo.z = (vReg[4] & 0xffffu) | (vReg[5] << 16);
            wlo.w = (vReg[6] & 0xffffu) | (vReg[7] << 16);
            whi.x = (vReg[0] >> 16) | (vReg[1] & 0xffff0000u);
            whi.y = (vReg[2] >> 16) | (vReg[3] & 0xffff0000u);
            whi.z = (vReg[4] >> 16) | (vReg[5] & 0xffff0000u);
            whi.w = (vReg[6] >> 16) | (vReg[7] & 0xffff0000u);
            *(uint4*)&vt_s[vd2][vjg * 8]     = wlo;
            *(uint4*)&vt_s[vd2 + 1][vjg * 8] = whi;
        }
#pragma unroll
        for (int ps = 0; ps < 4; ++ps)
            *(uint4*)&pw_s[srow + ps * 32][scol] = pReg[ps];
        __syncthreads();

        if (j0 + 64 < T_) prefetch(j0 + 64);   // overlap with compute below

        // ---- MFMA: content (ac·K) + skewed positional (ap·P) ----
        f32x4 Sc[4], G[5];
#pragma unroll
        for (int nt = 0; nt < 4; ++nt) Sc[nt] = (f32x4){0.f, 0.f, 0.f, 0.f};
#pragma unroll
        for (int ct = 0; ct < 5; ++ct) G[ct] = (f32x4){0.f, 0.f, 0.f, 0.f};
#pragma unroll
        for (int kc = 0; kc < 2; ++kc) {
#pragma unroll
            for (int nt = 0; nt < 4; ++nt) {
                short8 bk = *(const short8*)&k_s[nt * 16 + n16][kc * 32 + quad * 8];
                Sc[nt] = MFMA16(ac[kc], bk, Sc[nt]);
            }
#pragma unroll
            for (int ct = 0; ct < 5; ++ct) {
                short8 bp = *(const short8*)&pw_s[pwoff + ct * 16 + n16][kc * 32 + quad * 8];
                G[ct] = MFMA16(ap[kc], bp, G[ct]);
            }
        }
        // G -> wave-private gbuf[w] (no barrier: same-wave lockstep + lgkmcnt)
#pragma unroll
        for (int ct = 0; ct < 5; ++ct)
#pragma unroll
            for (int r = 0; r < 4; ++r)
                *(bf16*)&gbuf[w][quad * 4 + r][ct * 16 + n16] = f2b(G[ct][r]);

        // ---- assemble scores (base-2 domain), online softmax ----
        float sreg[4][4];
#pragma unroll
        for (int ct = 0; ct < 4; ++ct) {
#pragma unroll
            for (int r = 0; r < 4; ++r) {
                int ii = quad * 4 + r;
                int c  = ct * 16 + n16 - ii + 15;   // 0..78
                sreg[ct][r] = (Sc[ct][r] + bits2f(gbuf[w][ii][c])) * sc_scale;
            }
        }
        if (i0 == 0 && w == 0 && j0 == 960 && lane == 15)   // wrap (i=0, j=T-1)
            sreg[3][0] = (Sc[3][0] + wrap_s) * sc_scale;

        float rowsum[4], alpha[4];
#pragma unroll
        for (int r = 0; r < 4; ++r) {
            float m = fmaxf(fmaxf(sreg[0][r], sreg[1][r]), fmaxf(sreg[2][r], sreg[3][r]));
#pragma unroll
            for (int msk = 1; msk < 16; msk <<= 1) m = fmaxf(m, __shfl_xor(m, msk, 64));
            float mn = fmaxf(mrow[r], m);
            alpha[r] = exp2f(mrow[r] - mn);
            mrow[r] = mn;
            float rs = 0.f;
#pragma unroll
            for (int ct = 0; ct < 4; ++ct) {
                float pe = exp2f(sreg[ct][r] - mn);
                sreg[ct][r] = pe;
                rs += pe;
            }
#pragma unroll
            for (int msk = 1; msk < 16; msk <<= 1) rs += __shfl_xor(rs, msk, 64);
            rowsum[r] = rs;
        }
#pragma unroll
        for (int r = 0; r < 4; ++r) {
            lrow[r] = lrow[r] * alpha[r] + rowsum[r];
#pragma unroll
            for (int nt = 0; nt < 4; ++nt) O[nt][r] *= alpha[r];
        }
        // P -> gbuf[w] cols 0..63 (G already consumed; same-wave ordering)
#pragma unroll
        for (int ct = 0; ct < 4; ++ct)
#pragma unroll
            for (int r = 0; r < 4; ++r)
                *(bf16*)&gbuf[w][quad * 4 + r][ct * 16 + n16] = f2b(sreg[ct][r]);

        // ---- PV ----
#pragma unroll
        for (int kc = 0; kc < 2; ++kc) {
            short8 pa = *(const short8*)&gbuf[w][n16][kc * 32 + quad * 8];
#pragma unroll
            for (int nt = 0; nt < 4; ++nt) {
                short8 vb = *(const short8*)&vt_s[nt * 16 + n16][kc * 32 + quad * 8];
                O[nt] = MFMA16(pa, vb, O[nt]);
            }
        }
    }

#pragma unroll
    for (int r = 0; r < 4; ++r) {
        float inv = 1.f / lrow[r];
        int row = i0 + 16 * w + quad * 4 + r;
#pragma unroll
        for (int nt = 0; nt < 4; ++nt)
            o[(size_t)(b * T_ + row) * 512 + h64 + nt * 16 + n16] = f2b(O[nt][r] * inv);
    }
}

extern "C" void kernel_launch(void* const* d_in, const int* in_sizes, int n_in,
                              void* d_out, int out_size, void* d_ws, size_t ws_size,
                              hipStream_t stream) {
    (void)in_sizes; (void)n_in; (void)out_size;
    const float* x     = (const float*)d_in[0];
    const float* pos   = (const float*)d_in[1];
    const float* cb    = (const float*)d_in[2];
    const float* pb    = (const float*)d_in[3];
    const float* gamma = (const float*)d_in[4];
    const float* beta  = (const float*)d_in[5];
    const float* Wq    = (const float*)d_in[6];
    const float* bq    = (const float*)d_in[7];
    const float* Wk    = (const float*)d_in[8];
    const float* bk    = (const float*)d_in[9];
    const float* Wv    = (const float*)d_in[10];
    const float* bv    = (const float*)d_in[11];
    const float* Wp    = (const float*)d_in[12];
    const float* Wo    = (const float*)d_in[13];
    const float* bo    = (const float*)d_in[14];
    float* out = (float*)d_out;

    const int BT = B_ * T_;       // 4096

    const size_t sz_bt = (size_t)BT * D_;            // 2,097,152
    const size_t sz_bl = (size_t)(B_ * L_) * D_;     // 4,192,256
    const size_t sz_w  = 512 * 512;
    const size_t need  = (5 * sz_bt + sz_bl + 5 * sz_w) * sizeof(bf16) + 1536 * sizeof(float);
    if (ws_size < need) return;

    // ws layout: y | o | q | k | v | p | Wqkv_t | Wp_t | Wo_t | biasq
    bf16* y       = (bf16*)d_ws;
    bf16* o       = y + sz_bt;
    bf16* q       = y + 2 * sz_bt;
    bf16* k       = y + 3 * sz_bt;
    bf16* v       = y + 4 * sz_bt;
    bf16* p       = y + 5 * sz_bt;
    bf16* Wqkv_t  = p + sz_bl;
    bf16* Wp_t    = Wqkv_t + 3 * sz_w;
    bf16* Wo_t    = Wp_t + sz_w;
    float* biasq  = (float*)(Wo_t + sz_w);
    // pos_bf scratch lives in d_out (8,388,608 B f32 region; pos_bf needs
    // 8188*512*2 = 8,384,512 B; staging over-read caps at 8192*512*2 = exactly
    // the region size). gemm_out later overwrites every element of d_out.
    bf16* pos_bf  = (bf16*)d_out;

    prep_all<<<7429, 256, 0, stream>>>(Wq, Wk, Wv, Wp, Wo, bq, bk, bv, pos, x,
                                       gamma, beta, Wqkv_t, Wp_t, Wo_t, biasq, pos_bf, y);

    // qkv: [4096,512]x[512,1536] (384 blocks) + p: [8188,512]x[512,512] (256 blocks)
    gemm_qkvp<<<640, 256, 0, stream>>>(y, pos_bf, Wqkv_t, Wp_t, biasq, q, p, sz_bt);

    attn_mfma_kernel<<<dim3(T_ / 64, H_, B_), 256, 0, stream>>>(q, k, v, p, cb, pb, o);

    // out: [4096,512]x[512,512] + bo + x residual -> f32 d_out
    gemm_out<<<128, 256, 0, stream>>>(o, Wo_t, bo, x, out);
}